// Round 1
// baseline (1386.661 us; speedup 1.0000x reference)
//
#include <hip/hip_runtime.h>
#include <math.h>

// Problem constants
#define BB   8
#define NVV  10242
#define NFF  20480
#define EPSBN 1e-5f

// Gram kernel tiling: chunks of 64 columns, 161 tiles per batch, 8 batches = 1288 chunks,
// 322 blocks x 4 chunks each.
#define GRAM_BLOCKS 322

// ---------------------------------------------------------------------------
// K0: Gram = sum_{b,v} x[b,:,v] x[b,:,v]^T  (partials per block) + column sums
// ---------------------------------------------------------------------------
__global__ __launch_bounds__(256)
void gram_kernel(const float* __restrict__ x, float* __restrict__ gramPart,
                 float* __restrict__ xsumPart)
{
    __shared__ __align__(16) float Xs[128 * 69];   // pad 69 to break bank conflicts
    const int t = threadIdx.x;
    const int ti = t & 15, tj = t >> 4;
    float acc[8][8];
    float xs[8];
#pragma unroll
    for (int u = 0; u < 8; ++u) {
        xs[u] = 0.f;
#pragma unroll
        for (int w = 0; w < 8; ++w) acc[u][w] = 0.f;
    }
    for (int cc = blockIdx.x * 4; cc < blockIdx.x * 4 + 4; ++cc) {
        const int b = cc / 161, tb = cc % 161, v0 = tb * 64;
        for (int idx = t; idx < 128 * 64; idx += 256) {
            const int ci = idx >> 6, v = idx & 63;
            const int gv = v0 + v;
            Xs[ci * 69 + v] = (gv < NVV) ? x[((size_t)b * 128 + ci) * NVV + gv] : 0.f;
        }
        __syncthreads();
        for (int v = 0; v < 64; ++v) {
            float a_[8], b_[8];
#pragma unroll
            for (int u = 0; u < 8; ++u) a_[u] = Xs[(ti * 8 + u) * 69 + v];
#pragma unroll
            for (int w = 0; w < 8; ++w) b_[w] = Xs[(tj * 8 + w) * 69 + v];
#pragma unroll
            for (int u = 0; u < 8; ++u) xs[u] += a_[u];
#pragma unroll
            for (int u = 0; u < 8; ++u)
#pragma unroll
                for (int w = 0; w < 8; ++w)
                    acc[u][w] = fmaf(a_[u], b_[w], acc[u][w]);
        }
        __syncthreads();
    }
    float* gp = gramPart + (size_t)blockIdx.x * 16384;
#pragma unroll
    for (int u = 0; u < 8; ++u)
#pragma unroll
        for (int w = 0; w < 8; ++w)
            gp[(ti * 8 + u) * 128 + (tj * 8 + w)] = acc[u][w];
    if (tj == 0) {
#pragma unroll
        for (int u = 0; u < 8; ++u)
            xsumPart[(size_t)blockIdx.x * 128 + ti * 8 + u] = xs[u];
    }
}

// ---------------------------------------------------------------------------
// K0R: reduce Gram partials + xsum partials
// ---------------------------------------------------------------------------
__global__ void reduce_gram_kernel(const float* __restrict__ gp, const float* __restrict__ xp,
                                   float* __restrict__ Gram, float* __restrict__ xsum)
{
    const int tid = blockIdx.x * 256 + threadIdx.x;
    for (int e = tid; e < 16384; e += 64 * 256) {
        float s = 0.f;
        for (int i = 0; i < GRAM_BLOCKS; ++i) s += gp[(size_t)i * 16384 + e];
        Gram[e] = s;
    }
    if (blockIdx.x == 0 && threadIdx.x < 128) {
        float s = 0.f;
        for (int i = 0; i < GRAM_BLOCKS; ++i) s += xp[(size_t)i * 128 + threadIdx.x];
        xsum[threadIdx.x] = s;
    }
}

// ---------------------------------------------------------------------------
// K1: analytic BN folding for branch a (128 ch) and branch b (256 ch).
//     alpha = g * rsqrt(var+eps), beta = be - alpha * E[W x]   (biases cancel)
// ---------------------------------------------------------------------------
__global__ __launch_bounds__(128)
void stats_ab_kernel(const float* __restrict__ Gram, const float* __restrict__ xsum,
                     const float* __restrict__ w1a, const float* __restrict__ g1a,
                     const float* __restrict__ be1a,
                     const float* __restrict__ w1b, const float* __restrict__ g1b,
                     const float* __restrict__ be1b,
                     float* __restrict__ alpha_a, float* __restrict__ beta_a,
                     float* __restrict__ alpha_b, float* __restrict__ beta_b)
{
    const int t = threadIdx.x;
    const int cc = blockIdx.x;
    const float invN = 1.f / (float)(BB * NVV);
    const bool isA = cc < 128;
    const int c = isA ? cc : cc - 128;
    const float* Wrow = isA ? (w1a + (size_t)c * 128) : (w1b + (size_t)c * 128);
    __shared__ float Wr[128];
    __shared__ float red[4];
    Wr[t] = Wrow[t];
    __syncthreads();
    float gi = 0.f;
    const float* Grow = Gram + (size_t)t * 128;
    for (int j = 0; j < 128; ++j) gi = fmaf(Grow[j], Wr[j], gi);
    float pi = Wr[t] * gi * invN;
    float qi = (xsum[t] * invN) * Wr[t];
    for (int off = 32; off > 0; off >>= 1) {
        pi += __shfl_down(pi, off);
        qi += __shfl_down(qi, off);
    }
    const int wid = t >> 6;
    if ((t & 63) == 0) { red[wid] = pi; red[2 + wid] = qi; }
    __syncthreads();
    if (t == 0) {
        const float P = red[0] + red[1], Q = red[2] + red[3];
        const float var = P - Q * Q;
        const float g = isA ? g1a[c] : g1b[c];
        const float be = isA ? be1a[c] : be1b[c];
        const float a = g * rsqrtf(var + EPSBN);
        if (isA) { alpha_a[c] = a; beta_a[c] = be - a * Q; }
        else     { alpha_b[c] = a; beta_b[c] = be - a * Q; }
    }
}

// ---------------------------------------------------------------------------
// Conv kernels (GEMM M=128/tile, N=128 verts/tile, K=128).
// MODE 0: A=w1a, B=x [B,128,NV];  out = relu(alpha*dot+beta) -> h [B,NV,128] (transposed store)
// MODE 1: A=w1b, B=x;             out = alpha*dot+beta       -> x2 [B,256,NV]
// MODE 2: A=w3a, B=relu(alpha2*meshraw+beta2) [B,NV,128];    raw dot -> d_out [B,256,NV] + stat partials
// ---------------------------------------------------------------------------
template <int MODE>
__global__ __launch_bounds__(256)
void conv_kernel(const float* __restrict__ A, const float* __restrict__ Bsrc,
                 const float* __restrict__ alphaIn, const float* __restrict__ betaIn,
                 const float* __restrict__ alphaOut, const float* __restrict__ betaOut,
                 float* __restrict__ Out,
                 float* __restrict__ statSum, float* __restrict__ statSsq)
{
    const int t = threadIdx.x;
    const int tc = t & 15, tv = t >> 4;
    const int vblk = blockIdx.x, b = blockIdx.y, mt = blockIdx.z;
    const int v0 = vblk * 128;
    const int Mrow0 = mt * 128;
    __shared__ __align__(16) float smem[128 * 33 + 32 * 132];
    float* Ws = smem;              // [128][33]
    float* Xs = smem + 128 * 33;   // [32][132]
    float acc[8][8];
#pragma unroll
    for (int u = 0; u < 8; ++u)
#pragma unroll
        for (int w = 0; w < 8; ++w) acc[u][w] = 0.f;

    for (int kc = 0; kc < 128; kc += 32) {
        for (int idx = t; idx < 128 * 32; idx += 256) {
            const int c = idx >> 5, k = idx & 31;
            Ws[c * 33 + k] = A[(size_t)(Mrow0 + c) * 128 + kc + k];
        }
        if (MODE < 2) {
            for (int idx = t; idx < 32 * 128; idx += 256) {
                const int k = idx >> 7, v = idx & 127;
                const int gv = v0 + v;
                Xs[k * 132 + v] = (gv < NVV) ? Bsrc[((size_t)b * 128 + kc + k) * NVV + gv] : 0.f;
            }
        } else {
            for (int idx = t; idx < 32 * 128; idx += 256) {
                const int cidx = idx & 31, v = idx >> 5;
                const int gv = v0 + v;
                float val = 0.f;
                if (gv < NVV) {
                    const float m = Bsrc[((size_t)b * NVV + gv) * 128 + kc + cidx];
                    val = fmaxf(fmaf(alphaIn[kc + cidx], m, betaIn[kc + cidx]), 0.f);
                }
                Xs[cidx * 132 + v] = val;
            }
        }
        __syncthreads();
#pragma unroll 4
        for (int k = 0; k < 32; ++k) {
            float a_[8];
#pragma unroll
            for (int u = 0; u < 8; ++u) a_[u] = Ws[(tc * 8 + u) * 33 + k];
            const float4 xv0 = *reinterpret_cast<const float4*>(&Xs[k * 132 + tv * 8]);
            const float4 xv1 = *reinterpret_cast<const float4*>(&Xs[k * 132 + tv * 8 + 4]);
            const float x_[8] = {xv0.x, xv0.y, xv0.z, xv0.w, xv1.x, xv1.y, xv1.z, xv1.w};
#pragma unroll
            for (int u = 0; u < 8; ++u)
#pragma unroll
                for (int w = 0; w < 8; ++w)
                    acc[u][w] = fmaf(a_[u], x_[w], acc[u][w]);
        }
        __syncthreads();
    }

    if (MODE == 0) {
        float aO[8], bO[8];
#pragma unroll
        for (int u = 0; u < 8; ++u) { aO[u] = alphaOut[tc * 8 + u]; bO[u] = betaOut[tc * 8 + u]; }
#pragma unroll
        for (int w = 0; w < 8; ++w) {
            const int v = v0 + tv * 8 + w;
            if (v < NVV) {
                float r[8];
#pragma unroll
                for (int u = 0; u < 8; ++u) r[u] = fmaxf(fmaf(aO[u], acc[u][w], bO[u]), 0.f);
                float* p = Out + ((size_t)b * NVV + v) * 128 + tc * 8;
                *reinterpret_cast<float4*>(p)     = make_float4(r[0], r[1], r[2], r[3]);
                *reinterpret_cast<float4*>(p + 4) = make_float4(r[4], r[5], r[6], r[7]);
            }
        }
    } else {
        float psum[8], pssq[8];
        const int vbase = v0 + tv * 8;
#pragma unroll
        for (int u = 0; u < 8; ++u) {
            const int row = Mrow0 + tc * 8 + u;
            float vals[8];
#pragma unroll
            for (int w = 0; w < 8; ++w) {
                float v = acc[u][w];
                if (MODE == 1) v = fmaf(alphaOut[row], v, betaOut[row]);
                vals[w] = v;
            }
            float* p = Out + ((size_t)b * 256 + row) * NVV + vbase;
            if (vbase + 8 <= NVV) {
#pragma unroll
                for (int w2 = 0; w2 < 4; ++w2)
                    reinterpret_cast<float2*>(p)[w2] = make_float2(vals[2 * w2], vals[2 * w2 + 1]);
            } else {
                for (int w = 0; w < 8; ++w)
                    if (vbase + w < NVV) p[w] = vals[w];
            }
            if (MODE == 2) {
                float s = 0.f, q = 0.f;
#pragma unroll
                for (int w = 0; w < 8; ++w) {
                    if (vbase + w < NVV) { s += vals[w]; q = fmaf(vals[w], vals[w], q); }
                }
                psum[u] = s; pssq[u] = q;
            }
        }
        if (MODE == 2) {
            __syncthreads();
#pragma unroll
            for (int u = 0; u < 8; ++u) {
                smem[(tc * 8 + u) * 17 + tv]        = psum[u];
                smem[2176 + (tc * 8 + u) * 17 + tv] = pssq[u];
            }
            __syncthreads();
            if (t < 128) {
                float s = 0.f, q = 0.f;
                for (int i = 0; i < 16; ++i) { s += smem[t * 17 + i]; q += smem[2176 + t * 17 + i]; }
                const int slot = b * 81 + vblk;
                statSum[((size_t)mt * 648 + slot) * 128 + t] = s;
                statSsq[((size_t)mt * 648 + slot) * 128 + t] = q;
            }
        }
    }
}

// ---------------------------------------------------------------------------
// K4: fused mesh conv. Gathers (G/EW/NS fused, L, F2V fused) build feat[16][512]
// in LDS, then GEMM with coeffs [512,128] staged in LDS chunks.
// Output meshraw [B,NV,128] + per-block channel stats partials.
// ---------------------------------------------------------------------------
__global__ __launch_bounds__(256)
void mesh_kernel(const float* __restrict__ h, const float* __restrict__ coeffs,
                 const float* __restrict__ Lv, const int* __restrict__ Lc,
                 const float* __restrict__ Fv, const int* __restrict__ Fc,
                 const float* __restrict__ Gv, const int* __restrict__ Gc,
                 const float* __restrict__ EW, const float* __restrict__ NSm,
                 float* __restrict__ meshraw, float* __restrict__ msum, float* __restrict__ mssq)
{
    __shared__ __align__(16) float featS[16 * 512];
    __shared__ __align__(16) float Cs[64 * 128];
    const int t = threadIdx.x;
    const int b = blockIdx.y, v0 = blockIdx.x * 16;
    const float* hb = h + (size_t)b * NVV * 128;
    {
        const int c = t & 127, half = t >> 7;
        for (int vv = half; vv < 16; vv += 2) {
            const int v = v0 + vv;
            float id = 0.f, lap = 0.f, ew = 0.f, ns = 0.f;
            if (v < NVV) {
                id = hb[(size_t)v * 128 + c];
#pragma unroll
                for (int j = 0; j < 7; ++j)
                    lap = fmaf(Lv[v * 7 + j], hb[(size_t)Lc[v * 7 + j] * 128 + c], lap);
                for (int j = 0; j < 6; ++j) {
                    const int f = Fc[v * 6 + j];
                    const float fw = Fv[v * 6 + j];
                    float aew = 0.f, ans = 0.f;
#pragma unroll
                    for (int e = 0; e < 3; ++e) {
                        const int r3 = (e * NFF + f) * 3;
                        float g = Gv[r3] * hb[(size_t)Gc[r3] * 128 + c];
                        g = fmaf(Gv[r3 + 1], hb[(size_t)Gc[r3 + 1] * 128 + c], g);
                        g = fmaf(Gv[r3 + 2], hb[(size_t)Gc[r3 + 2] * 128 + c], g);
                        aew = fmaf(EW[f * 3 + e], g, aew);
                        ans = fmaf(NSm[f * 3 + e], g, ans);
                    }
                    ew = fmaf(fw, aew, ew);
                    ns = fmaf(fw, ans, ns);
                }
            }
            *reinterpret_cast<float4*>(&featS[vv * 512 + c * 4]) = make_float4(id, lap, ew, ns);
        }
    }
    __syncthreads();
    const int o = t & 127, grp = t >> 7;
    float acc[8];
#pragma unroll
    for (int u = 0; u < 8; ++u) acc[u] = 0.f;
    for (int kc = 0; kc < 512; kc += 64) {
        for (int i = t; i < 64 * 128; i += 256)
            Cs[i] = coeffs[(size_t)(kc + (i >> 7)) * 128 + (i & 127)];
        __syncthreads();
#pragma unroll 4
        for (int k = 0; k < 64; k += 4) {
            const float c0 = Cs[(k + 0) * 128 + o];
            const float c1 = Cs[(k + 1) * 128 + o];
            const float c2 = Cs[(k + 2) * 128 + o];
            const float c3 = Cs[(k + 3) * 128 + o];
#pragma unroll
            for (int u = 0; u < 8; ++u) {
                const float4 f4 = *reinterpret_cast<const float4*>(&featS[(grp * 8 + u) * 512 + kc + k]);
                acc[u] = fmaf(f4.x, c0, fmaf(f4.y, c1, fmaf(f4.z, c2, fmaf(f4.w, c3, acc[u]))));
            }
        }
        __syncthreads();
    }
    float s = 0.f, q = 0.f;
#pragma unroll
    for (int u = 0; u < 8; ++u) {
        const int v = v0 + grp * 8 + u;
        if (v < NVV) {
            meshraw[((size_t)b * NVV + v) * 128 + o] = acc[u];
            s += acc[u];
            q = fmaf(acc[u], acc[u], q);
        }
    }
    __syncthreads();
    featS[grp * 128 + o] = s;
    featS[256 + grp * 128 + o] = q;
    __syncthreads();
    if (t < 128) {
        const int blk = blockIdx.y * 641 + blockIdx.x;
        msum[(size_t)blk * 128 + t] = featS[t] + featS[128 + t];
        mssq[(size_t)blk * 128 + t] = featS[256 + t] + featS[384 + t];
    }
}

// ---------------------------------------------------------------------------
// finalize stats partials -> alpha/beta  (split=1: channel c -> [c>>7] half-array)
// ---------------------------------------------------------------------------
__global__ __launch_bounds__(256)
void finalize_stats_kernel(const float* __restrict__ s, const float* __restrict__ q, int count,
                           const float* __restrict__ g, const float* __restrict__ be,
                           float* __restrict__ alpha, float* __restrict__ beta, int split)
{
    const int c = blockIdx.x, t = threadIdx.x;
    const size_t base = split ? ((size_t)(c >> 7) * count * 128 + (c & 127)) : (size_t)c;
    float ls = 0.f, lq = 0.f;
    for (int i = t; i < count; i += 256) {
        ls += s[base + (size_t)i * 128];
        lq += q[base + (size_t)i * 128];
    }
    __shared__ float rs[256], rq[256];
    rs[t] = ls; rq[t] = lq;
    __syncthreads();
    for (int off = 128; off > 0; off >>= 1) {
        if (t < off) { rs[t] += rs[t + off]; rq[t] += rq[t + off]; }
        __syncthreads();
    }
    if (t == 0) {
        const float invN = 1.f / (float)(BB * NVV);
        const float mean = rs[0] * invN;
        const float var = rq[0] * invN - mean * mean;
        const float a = g[c] * rsqrtf(var + EPSBN);
        alpha[c] = a;
        beta[c] = be[c] - a * mean;
    }
}

// ---------------------------------------------------------------------------
// K8: out = relu(alpha3*x1raw + beta3 + x2)   in place on d_out
// ---------------------------------------------------------------------------
__global__ __launch_bounds__(256)
void final_kernel(float* __restrict__ out, const float* __restrict__ x2,
                  const float* __restrict__ alpha3, const float* __restrict__ beta3)
{
    const int blk = blockIdx.x;             // b*256 + o
    const int o = blk & 255;
    const float a = alpha3[o], bb = beta3[o];
    float2* po = reinterpret_cast<float2*>(out + (size_t)blk * NVV);
    const float2* p2 = reinterpret_cast<const float2*>(x2 + (size_t)blk * NVV);
    for (int i = threadIdx.x; i < NVV / 2; i += 256) {
        const float2 v1 = po[i];
        const float2 v2 = p2[i];
        po[i] = make_float2(fmaxf(fmaf(a, v1.x, bb) + v2.x, 0.f),
                            fmaxf(fmaf(a, v1.y, bb) + v2.y, 0.f));
    }
}

// ---------------------------------------------------------------------------
extern "C" void kernel_launch(void* const* d_in, const int* in_sizes, int n_in,
                              void* d_out, int out_size, void* d_ws, size_t ws_size,
                              hipStream_t stream)
{
    (void)in_sizes; (void)n_in; (void)out_size;
    const float* x      = (const float*)d_in[0];
    const float* w1a    = (const float*)d_in[1];
    const float* g1a    = (const float*)d_in[3];
    const float* be1a   = (const float*)d_in[4];
    const float* coeffs = (const float*)d_in[5];
    const float* g2a    = (const float*)d_in[6];
    const float* be2a   = (const float*)d_in[7];
    const float* w3a    = (const float*)d_in[8];
    const float* g3a    = (const float*)d_in[10];
    const float* be3a   = (const float*)d_in[11];
    const float* w1b    = (const float*)d_in[12];
    const float* g1b    = (const float*)d_in[14];
    const float* be1b   = (const float*)d_in[15];
    const float* Gv     = (const float*)d_in[16];
    const float* Lv     = (const float*)d_in[17];
    const float* Fv     = (const float*)d_in[18];
    const float* EW     = (const float*)d_in[19];
    const float* NSm    = (const float*)d_in[20];
    const int*   Gc     = (const int*)d_in[22];
    const int*   Lc     = (const int*)d_in[24];
    const int*   Fc     = (const int*)d_in[26];

    float* ws = (float*)d_ws;
    size_t off = 0;
    auto alloc = [&](size_t n) { float* p = ws + off; off += n; return p; };
    float* gramPart = alloc((size_t)GRAM_BLOCKS * 16384);
    float* xsumPart = alloc((size_t)GRAM_BLOCKS * 128);
    float* Gram     = alloc(16384);
    float* xsum     = alloc(128);
    float* alpha_a  = alloc(128);
    float* beta_a   = alloc(128);
    float* alpha_b  = alloc(256);
    float* beta_b   = alloc(256);
    float* alpha2   = alloc(128);
    float* beta2    = alloc(128);
    float* alpha3   = alloc(256);
    float* beta3    = alloc(256);
    float* h        = alloc((size_t)BB * NVV * 128);
    float* meshraw  = alloc((size_t)BB * NVV * 128);
    float* x2      = alloc((size_t)BB * 256 * NVV);
    float* msum     = alloc((size_t)5128 * 128);
    float* mssq     = alloc((size_t)5128 * 128);
    float* x1sum    = alloc((size_t)2 * 648 * 128);
    float* x1ssq    = alloc((size_t)2 * 648 * 128);
    if (off * sizeof(float) > ws_size) return;   // fail loud (validation will catch)

    gram_kernel<<<GRAM_BLOCKS, 256, 0, stream>>>(x, gramPart, xsumPart);
    reduce_gram_kernel<<<64, 256, 0, stream>>>(gramPart, xsumPart, Gram, xsum);
    stats_ab_kernel<<<384, 128, 0, stream>>>(Gram, xsum, w1a, g1a, be1a, w1b, g1b, be1b,
                                             alpha_a, beta_a, alpha_b, beta_b);
    conv_kernel<0><<<dim3(81, 8, 1), 256, 0, stream>>>(w1a, x, nullptr, nullptr,
                                                       alpha_a, beta_a, h, nullptr, nullptr);
    conv_kernel<1><<<dim3(81, 8, 2), 256, 0, stream>>>(w1b, x, nullptr, nullptr,
                                                       alpha_b, beta_b, x2, nullptr, nullptr);
    mesh_kernel<<<dim3(641, 8), 256, 0, stream>>>(h, coeffs, Lv, Lc, Fv, Fc, Gv, Gc, EW, NSm,
                                                  meshraw, msum, mssq);
    finalize_stats_kernel<<<128, 256, 0, stream>>>(msum, mssq, 5128, g2a, be2a, alpha2, beta2, 0);
    conv_kernel<2><<<dim3(81, 8, 2), 256, 0, stream>>>(w3a, meshraw, alpha2, beta2,
                                                       nullptr, nullptr, (float*)d_out,
                                                       x1sum, x1ssq);
    finalize_stats_kernel<<<256, 256, 0, stream>>>(x1sum, x1ssq, 648, g3a, be3a, alpha3, beta3, 1);
    final_kernel<<<2048, 256, 0, stream>>>((float*)d_out, x2, alpha3, beta3);
}

// Round 2
// 701.608 us; speedup vs baseline: 1.9764x; 1.9764x over previous
//
#include <hip/hip_runtime.h>
#include <math.h>

#define BB   8
#define NVV  10242
#define NFF  20480
#define EPSBN 1e-5f
#define GRAM_BLOCKS 322

typedef __attribute__((ext_vector_type(8))) short bf16x8_t;
typedef __attribute__((ext_vector_type(4))) float f32x4_t;

__device__ inline float bf2f(ushort u) {
    union { uint i; float f; } v; v.i = ((uint)u) << 16; return v.f;
}
__device__ inline ushort f2bf(float f) {
    union { float f; uint i; } v; v.f = f;
    const uint r = v.i + 0x7fffu + ((v.i >> 16) & 1u);
    return (ushort)(r >> 16);
}
__device__ inline void unpack2(uint w, float& lo, float& hi) {
    union { uint i; float f; } a, b;
    a.i = w << 16; b.i = w & 0xffff0000u;
    lo = a.f; hi = b.f;
}
__device__ inline uint pack2(float lo, float hi) {
    return (uint)f2bf(lo) | ((uint)f2bf(hi) << 16);
}
__device__ inline void fma8(const uint4 hv, const float w, float s[8]) {
    float lo, hi;
    unpack2(hv.x, lo, hi); s[0] = fmaf(w, lo, s[0]); s[1] = fmaf(w, hi, s[1]);
    unpack2(hv.y, lo, hi); s[2] = fmaf(w, lo, s[2]); s[3] = fmaf(w, hi, s[3]);
    unpack2(hv.z, lo, hi); s[4] = fmaf(w, lo, s[4]); s[5] = fmaf(w, hi, s[5]);
    unpack2(hv.w, lo, hi); s[6] = fmaf(w, lo, s[6]); s[7] = fmaf(w, hi, s[7]);
}
__device__ inline uint4 pack8(const float s[8]) {
    uint4 p;
    p.x = pack2(s[0], s[1]); p.y = pack2(s[2], s[3]);
    p.z = pack2(s[4], s[5]); p.w = pack2(s[6], s[7]);
    return p;
}

// ---------------------------------------------------------------------------
// K0: Gram = sum_{b,v} x[b,:,v] x[b,:,v]^T  (partials per block) + column sums
// ---------------------------------------------------------------------------
__global__ __launch_bounds__(256)
void gram_kernel(const float* __restrict__ x, float* __restrict__ gramPart,
                 float* __restrict__ xsumPart)
{
    __shared__ __align__(16) float Xs[128 * 69];
    const int t = threadIdx.x;
    const int ti = t & 15, tj = t >> 4;
    float acc[8][8];
    float xs[8];
#pragma unroll
    for (int u = 0; u < 8; ++u) {
        xs[u] = 0.f;
#pragma unroll
        for (int w = 0; w < 8; ++w) acc[u][w] = 0.f;
    }
    for (int cc = blockIdx.x * 4; cc < blockIdx.x * 4 + 4; ++cc) {
        const int b = cc / 161, tb = cc % 161, v0 = tb * 64;
        for (int idx = t; idx < 128 * 64; idx += 256) {
            const int ci = idx >> 6, v = idx & 63;
            const int gv = v0 + v;
            Xs[ci * 69 + v] = (gv < NVV) ? x[((size_t)b * 128 + ci) * NVV + gv] : 0.f;
        }
        __syncthreads();
        for (int v = 0; v < 64; ++v) {
            float a_[8], b_[8];
#pragma unroll
            for (int u = 0; u < 8; ++u) a_[u] = Xs[(ti * 8 + u) * 69 + v];
#pragma unroll
            for (int w = 0; w < 8; ++w) b_[w] = Xs[(tj * 8 + w) * 69 + v];
#pragma unroll
            for (int u = 0; u < 8; ++u) xs[u] += a_[u];
#pragma unroll
            for (int u = 0; u < 8; ++u)
#pragma unroll
                for (int w = 0; w < 8; ++w)
                    acc[u][w] = fmaf(a_[u], b_[w], acc[u][w]);
        }
        __syncthreads();
    }
    float* gp = gramPart + (size_t)blockIdx.x * 16384;
#pragma unroll
    for (int u = 0; u < 8; ++u)
#pragma unroll
        for (int w = 0; w < 8; ++w)
            gp[(ti * 8 + u) * 128 + (tj * 8 + w)] = acc[u][w];
    if (tj == 0) {
#pragma unroll
        for (int u = 0; u < 8; ++u)
            xsumPart[(size_t)blockIdx.x * 128 + ti * 8 + u] = xs[u];
    }
}

__global__ void reduce_gram_kernel(const float* __restrict__ gp, const float* __restrict__ xp,
                                   float* __restrict__ Gram, float* __restrict__ xsum)
{
    const int tid = blockIdx.x * 256 + threadIdx.x;
    for (int e = tid; e < 16384; e += 64 * 256) {
        float s = 0.f;
        for (int i = 0; i < GRAM_BLOCKS; ++i) s += gp[(size_t)i * 16384 + e];
        Gram[e] = s;
    }
    if (blockIdx.x == 0 && threadIdx.x < 128) {
        float s = 0.f;
        for (int i = 0; i < GRAM_BLOCKS; ++i) s += xp[(size_t)i * 128 + threadIdx.x];
        xsum[threadIdx.x] = s;
    }
}

// ---------------------------------------------------------------------------
// K1: analytic BN folding for conv1a (128 ch) and conv1b (256 ch)
// ---------------------------------------------------------------------------
__global__ __launch_bounds__(128)
void stats_ab_kernel(const float* __restrict__ Gram, const float* __restrict__ xsum,
                     const float* __restrict__ w1a, const float* __restrict__ g1a,
                     const float* __restrict__ be1a,
                     const float* __restrict__ w1b, const float* __restrict__ g1b,
                     const float* __restrict__ be1b,
                     float* __restrict__ alpha_a, float* __restrict__ beta_a,
                     float* __restrict__ alpha_b, float* __restrict__ beta_b)
{
    const int t = threadIdx.x;
    const int cc = blockIdx.x;
    const float invN = 1.f / (float)(BB * NVV);
    const bool isA = cc < 128;
    const int c = isA ? cc : cc - 128;
    const float* Wrow = isA ? (w1a + (size_t)c * 128) : (w1b + (size_t)c * 128);
    __shared__ float Wr[128];
    __shared__ float red[4];
    Wr[t] = Wrow[t];
    __syncthreads();
    float gi = 0.f;
    const float* Grow = Gram + (size_t)t * 128;
    for (int j = 0; j < 128; ++j) gi = fmaf(Grow[j], Wr[j], gi);
    float pi = Wr[t] * gi * invN;
    float qi = (xsum[t] * invN) * Wr[t];
    for (int off = 32; off > 0; off >>= 1) {
        pi += __shfl_down(pi, off);
        qi += __shfl_down(qi, off);
    }
    const int wid = t >> 6;
    if ((t & 63) == 0) { red[wid] = pi; red[2 + wid] = qi; }
    __syncthreads();
    if (t == 0) {
        const float P = red[0] + red[1], Q = red[2] + red[3];
        const float var = P - Q * Q;
        const float g = isA ? g1a[c] : g1b[c];
        const float be = isA ? be1a[c] : be1b[c];
        const float a = g * rsqrtf(var + EPSBN);
        if (isA) { alpha_a[c] = a; beta_a[c] = be - a * Q; }
        else     { alpha_b[c] = a; beta_b[c] = be - a * Q; }
    }
}

// ---------------------------------------------------------------------------
// Conv kernels (VALU fp32 GEMM, K=128).
// MODE 0: A=w1a, B=x fp32 [B,128,NV]; out=relu(a*dot+b) -> h bf16 [B,NV,128]
// MODE 1: A=w1b, B=x fp32;            out=a*dot+b       -> x2 bf16 [B,256,NV]
// MODE 2: A=w3a, B=relu(a2*meshraw_bf16+b2) [B,NV,128]; raw -> d_out fp32 [B,256,NV] + stats
// ---------------------------------------------------------------------------
template <int MODE>
__global__ __launch_bounds__(256)
void conv_kernel(const float* __restrict__ A, const void* __restrict__ Bsrc_,
                 const float* __restrict__ alphaIn, const float* __restrict__ betaIn,
                 const float* __restrict__ alphaOut, const float* __restrict__ betaOut,
                 void* __restrict__ Out_,
                 float* __restrict__ statSum, float* __restrict__ statSsq)
{
    const int t = threadIdx.x;
    const int tc = t & 15, tv = t >> 4;
    const int vblk = blockIdx.x, b = blockIdx.y, mt = blockIdx.z;
    const int v0 = vblk * 128;
    const int Mrow0 = mt * 128;
    __shared__ __align__(16) float smem[128 * 33 + 32 * 132];
    float* Ws = smem;
    float* Xs = smem + 128 * 33;
    float acc[8][8];
#pragma unroll
    for (int u = 0; u < 8; ++u)
#pragma unroll
        for (int w = 0; w < 8; ++w) acc[u][w] = 0.f;

    for (int kc = 0; kc < 128; kc += 32) {
        for (int idx = t; idx < 128 * 32; idx += 256) {
            const int c = idx >> 5, k = idx & 31;
            Ws[c * 33 + k] = A[(size_t)(Mrow0 + c) * 128 + kc + k];
        }
        if (MODE < 2) {
            const float* Bx = (const float*)Bsrc_;
            for (int idx = t; idx < 32 * 128; idx += 256) {
                const int k = idx >> 7, v = idx & 127;
                const int gv = v0 + v;
                Xs[k * 132 + v] = (gv < NVV) ? Bx[((size_t)b * 128 + kc + k) * NVV + gv] : 0.f;
            }
        } else {
            const ushort* Bm = (const ushort*)Bsrc_;
            for (int idx = t; idx < 32 * 128; idx += 256) {
                const int cidx = idx & 31, v = idx >> 5;
                const int gv = v0 + v;
                float val = 0.f;
                if (gv < NVV) {
                    const float m = bf2f(Bm[((size_t)b * NVV + gv) * 128 + kc + cidx]);
                    val = fmaxf(fmaf(alphaIn[kc + cidx], m, betaIn[kc + cidx]), 0.f);
                }
                Xs[cidx * 132 + v] = val;
            }
        }
        __syncthreads();
#pragma unroll 4
        for (int k = 0; k < 32; ++k) {
            float a_[8];
#pragma unroll
            for (int u = 0; u < 8; ++u) a_[u] = Ws[(tc * 8 + u) * 33 + k];
            const float4 xv0 = *reinterpret_cast<const float4*>(&Xs[k * 132 + tv * 8]);
            const float4 xv1 = *reinterpret_cast<const float4*>(&Xs[k * 132 + tv * 8 + 4]);
            const float x_[8] = {xv0.x, xv0.y, xv0.z, xv0.w, xv1.x, xv1.y, xv1.z, xv1.w};
#pragma unroll
            for (int u = 0; u < 8; ++u)
#pragma unroll
                for (int w = 0; w < 8; ++w)
                    acc[u][w] = fmaf(a_[u], x_[w], acc[u][w]);
        }
        __syncthreads();
    }

    if (MODE == 0) {
        ushort* Oh = (ushort*)Out_;
        float aO[8], bO[8];
#pragma unroll
        for (int u = 0; u < 8; ++u) { aO[u] = alphaOut[tc * 8 + u]; bO[u] = betaOut[tc * 8 + u]; }
#pragma unroll
        for (int w = 0; w < 8; ++w) {
            const int v = v0 + tv * 8 + w;
            if (v < NVV) {
                float r[8];
#pragma unroll
                for (int u = 0; u < 8; ++u) r[u] = fmaxf(fmaf(aO[u], acc[u][w], bO[u]), 0.f);
                ushort* p = Oh + ((size_t)b * NVV + v) * 128 + tc * 8;
                *reinterpret_cast<uint4*>(p) = pack8(r);
            }
        }
    } else {
        float psum[8], pssq[8];
        const int vbase = v0 + tv * 8;
#pragma unroll
        for (int u = 0; u < 8; ++u) {
            const int row = Mrow0 + tc * 8 + u;
            float vals[8];
#pragma unroll
            for (int w = 0; w < 8; ++w) {
                float v = acc[u][w];
                if (MODE == 1) v = fmaf(alphaOut[row], v, betaOut[row]);
                vals[w] = v;
            }
            if (MODE == 1) {
                ushort* p = (ushort*)Out_ + ((size_t)b * 256 + row) * NVV + vbase;
                if (vbase + 8 <= NVV) {
                    uint* pu = (uint*)p;
#pragma unroll
                    for (int w2 = 0; w2 < 4; ++w2)
                        pu[w2] = pack2(vals[2 * w2], vals[2 * w2 + 1]);
                } else {
                    for (int w = 0; w < 8; ++w)
                        if (vbase + w < NVV) p[w] = f2bf(vals[w]);
                }
            } else {
                float* p = (float*)Out_ + ((size_t)b * 256 + row) * NVV + vbase;
                if (vbase + 8 <= NVV) {
#pragma unroll
                    for (int w2 = 0; w2 < 4; ++w2)
                        reinterpret_cast<float2*>(p)[w2] = make_float2(vals[2 * w2], vals[2 * w2 + 1]);
                } else {
                    for (int w = 0; w < 8; ++w)
                        if (vbase + w < NVV) p[w] = vals[w];
                }
                float s = 0.f, q = 0.f;
#pragma unroll
                for (int w = 0; w < 8; ++w) {
                    if (vbase + w < NVV) { s += vals[w]; q = fmaf(vals[w], vals[w], q); }
                }
                psum[u] = s; pssq[u] = q;
            }
        }
        if (MODE == 2) {
            __syncthreads();
#pragma unroll
            for (int u = 0; u < 8; ++u) {
                smem[(tc * 8 + u) * 17 + tv]        = psum[u];
                smem[2176 + (tc * 8 + u) * 17 + tv] = pssq[u];
            }
            __syncthreads();
            if (t < 128) {
                float s = 0.f, q = 0.f;
                for (int i = 0; i < 16; ++i) { s += smem[t * 17 + i]; q += smem[2176 + t * 17 + i]; }
                const int slot = b * 81 + vblk;
                statSum[((size_t)mt * 648 + slot) * 128 + t] = s;
                statSsq[((size_t)mt * 648 + slot) * 128 + t] = q;
            }
        }
    }
}

// ---------------------------------------------------------------------------
// Face kernel: gf_ew/gf_ns per face from h (9 shared gathers/face).
// gf layout [B][NF][2][128] bf16.  1 wave = 1 face, lane = 2 channels.
// ---------------------------------------------------------------------------
__global__ __launch_bounds__(256)
void face_kernel(const ushort* __restrict__ h, const float* __restrict__ Gv,
                 const int* __restrict__ Gc, const float* __restrict__ EW,
                 const float* __restrict__ NSm, ushort* __restrict__ gf)
{
    const int t = threadIdx.x;
    const int lane = t & 63, wid = t >> 6;
    const int f = blockIdx.x * 4 + wid;
    const int b = blockIdx.y;
    const uint* hb = (const uint*)h + (size_t)b * NVV * 64;
    float ewx = 0.f, ewy = 0.f, nsx = 0.f, nsy = 0.f;
#pragma unroll
    for (int e = 0; e < 3; ++e) {
        const size_t r3 = ((size_t)e * NFF + f) * 3;
        float gx = 0.f, gy = 0.f;
#pragma unroll
        for (int j = 0; j < 3; ++j) {
            const float w = Gv[r3 + j];
            const int col = Gc[r3 + j];
            const uint hv = hb[(size_t)col * 64 + lane];
            float lo, hi; unpack2(hv, lo, hi);
            gx = fmaf(w, lo, gx); gy = fmaf(w, hi, gy);
        }
        const float we = EW[f * 3 + e], wn = NSm[f * 3 + e];
        ewx = fmaf(we, gx, ewx); ewy = fmaf(we, gy, ewy);
        nsx = fmaf(wn, gx, nsx); nsy = fmaf(wn, gy, nsy);
    }
    uint* go = (uint*)gf + ((size_t)b * NFF + f) * 128;   // 2 slabs * 64 uints
    go[lane]      = pack2(ewx, ewy);
    go[64 + lane] = pack2(nsx, nsy);
}

// ---------------------------------------------------------------------------
// mesh_gemm: per block 128 vertex-rows. Builds feat tile [128][64] bf16 in LDS
// by gathers (id/lap from h, ew/ns from gf), stages coeffs chunk, MFMA 16x16x32.
// feat k-order: k = q*128 + c  (coeffs row = c*4 + q). Output meshraw bf16 + stats.
// ---------------------------------------------------------------------------
__global__ __launch_bounds__(256)
void mesh_gemm_kernel(const ushort* __restrict__ h, const ushort* __restrict__ gf,
                      const float* __restrict__ coeffs,
                      const float* __restrict__ Lv, const int* __restrict__ Lc,
                      const float* __restrict__ Fv, const int* __restrict__ Fc,
                      ushort* __restrict__ meshraw,
                      float* __restrict__ msum, float* __restrict__ mssq)
{
    __shared__ __align__(16) ushort As[128 * 64];
    __shared__ __align__(16) ushort Bs[128 * 64];
    __shared__ float statS[256];
    __shared__ float statQ[256];
    const int t = threadIdx.x;
    const int b = blockIdx.y;
    const int v0 = blockIdx.x * 128;
    const int l = t & 63, wid = t >> 6;
    const int wr = wid >> 1, wc = wid & 1;
    const int l15 = l & 15, l4 = l >> 4;
    const size_t hb = (size_t)b * NVV * 128;
    f32x4_t acc[4][4];
#pragma unroll
    for (int m = 0; m < 4; ++m)
#pragma unroll
        for (int n = 0; n < 4; ++n) acc[m][n] = (f32x4_t){0.f, 0.f, 0.f, 0.f};

    for (int chunk = 0; chunk < 8; ++chunk) {
        const int q = chunk >> 1, c0 = (chunk & 1) << 6;
        // ---- stage A: feat[r][kk] = featval(q, c0+kk), swizzled ----
#pragma unroll
        for (int i = 0; i < 4; ++i) {
            const int item = t + (i << 8);
            const int r = item >> 3, piece = item & 7;
            const int v = v0 + r;
            const int cb = c0 + piece * 8;
            uint4 pk = make_uint4(0u, 0u, 0u, 0u);
            if (v < NVV) {
                if (q == 0) {
                    pk = *reinterpret_cast<const uint4*>(h + hb + (size_t)v * 128 + cb);
                } else if (q == 1) {
                    float s[8] = {0.f, 0.f, 0.f, 0.f, 0.f, 0.f, 0.f, 0.f};
#pragma unroll
                    for (int j = 0; j < 7; ++j) {
                        const float w = Lv[v * 7 + j];
                        const int col = Lc[v * 7 + j];
                        const uint4 hv = *reinterpret_cast<const uint4*>(h + hb + (size_t)col * 128 + cb);
                        fma8(hv, w, s);
                    }
                    pk = pack8(s);
                } else {
                    const int slab = q - 2;
                    float s[8] = {0.f, 0.f, 0.f, 0.f, 0.f, 0.f, 0.f, 0.f};
#pragma unroll
                    for (int j = 0; j < 6; ++j) {
                        const float w = Fv[v * 6 + j];
                        const int f = Fc[v * 6 + j];
                        const uint4 gv = *reinterpret_cast<const uint4*>(
                            gf + (((size_t)b * NFF + f) * 2 + slab) * 128 + cb);
                        fma8(gv, w, s);
                    }
                    pk = pack8(s);
                }
            }
            const int byte = (r << 7) + (piece << 4);
            *reinterpret_cast<uint4*>((char*)As + (byte ^ ((r & 7) << 4))) = pk;
        }
        // ---- stage B: Bs[o][kk] = coeffs[(c0+kk)*4+q][o], swizzled ----
#pragma unroll
        for (int i = 0; i < 16; ++i) {
            const int item = t + (i << 8);           // 4096 uint pairs
            const int o = item & 127, kk = (item >> 7) << 1;
            const int row0 = (c0 + kk) * 4 + q;
            const uint pw = pack2(coeffs[(size_t)row0 * 128 + o],
                                  coeffs[(size_t)(row0 + 4) * 128 + o]);
            const int byte = (o << 7) + (kk << 1);
            *reinterpret_cast<uint*>((char*)Bs + (byte ^ ((o & 7) << 4))) = pw;
        }
        __syncthreads();
        // ---- MFMA ----
#pragma unroll
        for (int kk2 = 0; kk2 < 2; ++kk2) {
            bf16x8_t af[4], bfr[4];
#pragma unroll
            for (int m = 0; m < 4; ++m) {
                const int row = wr * 64 + m * 16 + l15;
                const int byte = (row << 7) + (kk2 << 6) + (l4 << 4);
                af[m] = *reinterpret_cast<const bf16x8_t*>((const char*)As + (byte ^ ((row & 7) << 4)));
            }
#pragma unroll
            for (int n = 0; n < 4; ++n) {
                const int o = wc * 64 + n * 16 + l15;
                const int byte = (o << 7) + (kk2 << 6) + (l4 << 4);
                bfr[n] = *reinterpret_cast<const bf16x8_t*>((const char*)Bs + (byte ^ ((o & 7) << 4)));
            }
#pragma unroll
            for (int m = 0; m < 4; ++m)
#pragma unroll
                for (int n = 0; n < 4; ++n)
                    acc[m][n] = __builtin_amdgcn_mfma_f32_16x16x32_bf16(af[m], bfr[n], acc[m][n], 0, 0, 0);
        }
        __syncthreads();
    }
    // ---- epilogue: store meshraw bf16 + per-channel stats ----
    float ssum[4] = {0.f, 0.f, 0.f, 0.f}, sssq[4] = {0.f, 0.f, 0.f, 0.f};
#pragma unroll
    for (int m = 0; m < 4; ++m) {
#pragma unroll
        for (int j = 0; j < 4; ++j) {
            const int row = wr * 64 + m * 16 + l4 * 4 + j;
            const int v = v0 + row;
            if (v < NVV) {
                ushort* mp = meshraw + hb + (size_t)v * 128 + wc * 64 + l15;
#pragma unroll
                for (int n = 0; n < 4; ++n) {
                    const float val = acc[m][n][j];
                    mp[n * 16] = f2bf(val);
                    ssum[n] += val;
                    sssq[n] = fmaf(val, val, sssq[n]);
                }
            }
        }
    }
#pragma unroll
    for (int n = 0; n < 4; ++n) {
        ssum[n] += __shfl_xor(ssum[n], 16); ssum[n] += __shfl_xor(ssum[n], 32);
        sssq[n] += __shfl_xor(sssq[n], 16); sssq[n] += __shfl_xor(sssq[n], 32);
    }
    if (l < 16) {
#pragma unroll
        for (int n = 0; n < 4; ++n) {
            statS[wr * 128 + wc * 64 + n * 16 + l] = ssum[n];
            statQ[wr * 128 + wc * 64 + n * 16 + l] = sssq[n];
        }
    }
    __syncthreads();
    if (t < 128) {
        const int blk = b * 81 + blockIdx.x;
        msum[(size_t)blk * 128 + t] = statS[t] + statS[128 + t];
        mssq[(size_t)blk * 128 + t] = statQ[t] + statQ[128 + t];
    }
}

// ---------------------------------------------------------------------------
__global__ __launch_bounds__(256)
void finalize_stats_kernel(const float* __restrict__ s, const float* __restrict__ q, int count,
                           const float* __restrict__ g, const float* __restrict__ be,
                           float* __restrict__ alpha, float* __restrict__ beta, int split)
{
    const int c = blockIdx.x, t = threadIdx.x;
    const size_t base = split ? ((size_t)(c >> 7) * count * 128 + (c & 127)) : (size_t)c;
    float ls = 0.f, lq = 0.f;
    for (int i = t; i < count; i += 256) {
        ls += s[base + (size_t)i * 128];
        lq += q[base + (size_t)i * 128];
    }
    __shared__ float rs[256], rq[256];
    rs[t] = ls; rq[t] = lq;
    __syncthreads();
    for (int off = 128; off > 0; off >>= 1) {
        if (t < off) { rs[t] += rs[t + off]; rq[t] += rq[t + off]; }
        __syncthreads();
    }
    if (t == 0) {
        const float invN = 1.f / (float)(BB * NVV);
        const float mean = rs[0] * invN;
        const float var = rq[0] * invN - mean * mean;
        const float a = g[c] * rsqrtf(var + EPSBN);
        alpha[c] = a;
        beta[c] = be[c] - a * mean;
    }
}

// ---------------------------------------------------------------------------
// K8: out = relu(alpha3*x1raw + beta3 + x2)   in place on d_out  (x2 bf16)
// ---------------------------------------------------------------------------
__global__ __launch_bounds__(256)
void final_kernel(float* __restrict__ out, const ushort* __restrict__ x2,
                  const float* __restrict__ alpha3, const float* __restrict__ beta3)
{
    const int blk = blockIdx.x;
    const int o = blk & 255;
    const float a = alpha3[o], bb = beta3[o];
    float2* po = reinterpret_cast<float2*>(out + (size_t)blk * NVV);
    const uint* p2 = reinterpret_cast<const uint*>(x2 + (size_t)blk * NVV);
    for (int i = threadIdx.x; i < NVV / 2; i += 256) {
        const float2 v1 = po[i];
        float lo, hi; unpack2(p2[i], lo, hi);
        po[i] = make_float2(fmaxf(fmaf(a, v1.x, bb) + lo, 0.f),
                            fmaxf(fmaf(a, v1.y, bb) + hi, 0.f));
    }
}

// ---------------------------------------------------------------------------
extern "C" void kernel_launch(void* const* d_in, const int* in_sizes, int n_in,
                              void* d_out, int out_size, void* d_ws, size_t ws_size,
                              hipStream_t stream)
{
    (void)in_sizes; (void)n_in; (void)out_size;
    const float* x      = (const float*)d_in[0];
    const float* w1a    = (const float*)d_in[1];
    const float* g1a    = (const float*)d_in[3];
    const float* be1a   = (const float*)d_in[4];
    const float* coeffs = (const float*)d_in[5];
    const float* g2a    = (const float*)d_in[6];
    const float* be2a   = (const float*)d_in[7];
    const float* w3a    = (const float*)d_in[8];
    const float* g3a    = (const float*)d_in[10];
    const float* be3a   = (const float*)d_in[11];
    const float* w1b    = (const float*)d_in[12];
    const float* g1b    = (const float*)d_in[14];
    const float* be1b   = (const float*)d_in[15];
    const float* Gv     = (const float*)d_in[16];
    const float* Lv     = (const float*)d_in[17];
    const float* Fv     = (const float*)d_in[18];
    const float* EW     = (const float*)d_in[19];
    const float* NSm    = (const float*)d_in[20];
    const int*   Gc     = (const int*)d_in[22];
    const int*   Lc     = (const int*)d_in[24];
    const int*   Fc     = (const int*)d_in[26];

    char* base = (char*)d_ws;
    size_t off = 0;
    auto alloc = [&](size_t bytes) { char* p = base + off; off += (bytes + 255) & ~(size_t)255; return p; };

    // region0: gramPart+xsumPart (early) aliased with gf (late)
    const size_t gfBytes = (size_t)BB * NFF * 2 * 128 * 2;       // 83.9 MB
    char* region0   = alloc(gfBytes);
    float* gramPart = (float*)region0;
    float* xsumPart = (float*)(region0 + (size_t)GRAM_BLOCKS * 16384 * 4);
    ushort* gf      = (ushort*)region0;

    ushort* h       = (ushort*)alloc((size_t)BB * NVV * 128 * 2);
    ushort* meshraw = (ushort*)alloc((size_t)BB * NVV * 128 * 2);
    ushort* x2      = (ushort*)alloc((size_t)BB * 256 * NVV * 2);
    float* Gram     = (float*)alloc(16384 * 4);
    float* xsum     = (float*)alloc(128 * 4);
    float* alpha_a  = (float*)alloc(128 * 4);
    float* beta_a   = (float*)alloc(128 * 4);
    float* alpha_b  = (float*)alloc(256 * 4);
    float* beta_b   = (float*)alloc(256 * 4);
    float* alpha2   = (float*)alloc(128 * 4);
    float* beta2    = (float*)alloc(128 * 4);
    float* alpha3   = (float*)alloc(256 * 4);
    float* beta3    = (float*)alloc(256 * 4);
    float* msum     = (float*)alloc((size_t)648 * 128 * 4);
    float* mssq     = (float*)alloc((size_t)648 * 128 * 4);
    float* x1sum    = (float*)alloc((size_t)2 * 648 * 128 * 4);
    float* x1ssq    = (float*)alloc((size_t)2 * 648 * 128 * 4);
    if (off > ws_size) return;   // fail loud (validation will catch)

    gram_kernel<<<GRAM_BLOCKS, 256, 0, stream>>>(x, gramPart, xsumPart);
    reduce_gram_kernel<<<64, 256, 0, stream>>>(gramPart, xsumPart, Gram, xsum);
    stats_ab_kernel<<<384, 128, 0, stream>>>(Gram, xsum, w1a, g1a, be1a, w1b, g1b, be1b,
                                             alpha_a, beta_a, alpha_b, beta_b);
    conv_kernel<0><<<dim3(81, 8, 1), 256, 0, stream>>>(w1a, x, nullptr, nullptr,
                                                       alpha_a, beta_a, h, nullptr, nullptr);
    conv_kernel<1><<<dim3(81, 8, 2), 256, 0, stream>>>(w1b, x, nullptr, nullptr,
                                                       alpha_b, beta_b, x2, nullptr, nullptr);
    face_kernel<<<dim3(NFF / 4, 8), 256, 0, stream>>>(h, Gv, Gc, EW, NSm, gf);
    mesh_gemm_kernel<<<dim3(81, 8), 256, 0, stream>>>(h, gf, coeffs, Lv, Lc, Fv, Fc,
                                                      meshraw, msum, mssq);
    finalize_stats_kernel<<<128, 256, 0, stream>>>(msum, mssq, 648, g2a, be2a, alpha2, beta2, 0);
    conv_kernel<2><<<dim3(81, 8, 2), 256, 0, stream>>>(w3a, meshraw, alpha2, beta2,
                                                       nullptr, nullptr, d_out, x1sum, x1ssq);
    finalize_stats_kernel<<<256, 256, 0, stream>>>(x1sum, x1ssq, 648, g3a, be3a, alpha3, beta3, 1);
    final_kernel<<<2048, 256, 0, stream>>>((float*)d_out, x2, alpha3, beta3);
}

// Round 3
// 443.996 us; speedup vs baseline: 3.1231x; 1.5802x over previous
//
#include <hip/hip_runtime.h>
#include <math.h>

#define BB   8
#define NVV  10242
#define NFF  20480
#define EPSBN 1e-5f
#define GRAM_BLOCKS 322

typedef __attribute__((ext_vector_type(8))) short bf16x8_t;
typedef __attribute__((ext_vector_type(4))) float f32x4_t;

__device__ inline float bf2f(ushort u) {
    union { uint i; float f; } v; v.i = ((uint)u) << 16; return v.f;
}
__device__ inline ushort f2bf(float f) {
    union { float f; uint i; } v; v.f = f;
    const uint r = v.i + 0x7fffu + ((v.i >> 16) & 1u);
    return (ushort)(r >> 16);
}
__device__ inline void unpack2(uint w, float& lo, float& hi) {
    union { uint i; float f; } a, b;
    a.i = w << 16; b.i = w & 0xffff0000u;
    lo = a.f; hi = b.f;
}
__device__ inline uint pack2(float lo, float hi) {
    return (uint)f2bf(lo) | ((uint)f2bf(hi) << 16);
}
__device__ inline void fma8(const uint4 hv, const float w, float s[8]) {
    float lo, hi;
    unpack2(hv.x, lo, hi); s[0] = fmaf(w, lo, s[0]); s[1] = fmaf(w, hi, s[1]);
    unpack2(hv.y, lo, hi); s[2] = fmaf(w, lo, s[2]); s[3] = fmaf(w, hi, s[3]);
    unpack2(hv.z, lo, hi); s[4] = fmaf(w, lo, s[4]); s[5] = fmaf(w, hi, s[5]);
    unpack2(hv.w, lo, hi); s[6] = fmaf(w, lo, s[6]); s[7] = fmaf(w, hi, s[7]);
}
__device__ inline uint4 pack8(const float s[8]) {
    uint4 p;
    p.x = pack2(s[0], s[1]); p.y = pack2(s[2], s[3]);
    p.z = pack2(s[4], s[5]); p.w = pack2(s[6], s[7]);
    return p;
}

// ---------------------------------------------------------------------------
// K0: Gram partials + column sums + xT (bf16 vert-major transpose of x)
// ---------------------------------------------------------------------------
__global__ __launch_bounds__(256)
void gram_kernel(const float* __restrict__ x, float* __restrict__ gramPart,
                 float* __restrict__ xsumPart, uint* __restrict__ xTu)
{
    __shared__ __align__(16) float Xs[128 * 69];
    const int t = threadIdx.x;
    const int ti = t & 15, tj = t >> 4;
    float acc[8][8];
    float xs[8];
#pragma unroll
    for (int u = 0; u < 8; ++u) {
        xs[u] = 0.f;
#pragma unroll
        for (int w = 0; w < 8; ++w) acc[u][w] = 0.f;
    }
    for (int cc = blockIdx.x * 4; cc < blockIdx.x * 4 + 4; ++cc) {
        const int b = cc / 161, tb = cc % 161, v0 = tb * 64;
        for (int idx = t; idx < 128 * 64; idx += 256) {
            const int ci = idx >> 6, v = idx & 63;
            const int gv = v0 + v;
            Xs[ci * 69 + v] = (gv < NVV) ? x[((size_t)b * 128 + ci) * NVV + gv] : 0.f;
        }
        __syncthreads();
        // write xT bf16 [B][NV][128]
        for (int idx = t; idx < 64 * 64; idx += 256) {
            const int v = idx >> 6, cp = idx & 63;
            const int gv = v0 + v;
            if (gv < NVV) {
                xTu[((size_t)b * NVV + gv) * 64 + cp] =
                    pack2(Xs[(2 * cp) * 69 + v], Xs[(2 * cp + 1) * 69 + v]);
            }
        }
        for (int v = 0; v < 64; ++v) {
            float a_[8], b_[8];
#pragma unroll
            for (int u = 0; u < 8; ++u) a_[u] = Xs[(ti * 8 + u) * 69 + v];
#pragma unroll
            for (int w = 0; w < 8; ++w) b_[w] = Xs[(tj * 8 + w) * 69 + v];
#pragma unroll
            for (int u = 0; u < 8; ++u) xs[u] += a_[u];
#pragma unroll
            for (int u = 0; u < 8; ++u)
#pragma unroll
                for (int w = 0; w < 8; ++w)
                    acc[u][w] = fmaf(a_[u], b_[w], acc[u][w]);
        }
        __syncthreads();
    }
    float* gp = gramPart + (size_t)blockIdx.x * 16384;
#pragma unroll
    for (int u = 0; u < 8; ++u)
#pragma unroll
        for (int w = 0; w < 8; ++w)
            gp[(ti * 8 + u) * 128 + (tj * 8 + w)] = acc[u][w];
    if (tj == 0) {
#pragma unroll
        for (int u = 0; u < 8; ++u)
            xsumPart[(size_t)blockIdx.x * 128 + ti * 8 + u] = xs[u];
    }
}

__global__ void reduce_gram_kernel(const float* __restrict__ gp, const float* __restrict__ xp,
                                   float* __restrict__ Gram, float* __restrict__ xsum)
{
    const int tid = blockIdx.x * 256 + threadIdx.x;
    for (int e = tid; e < 16384; e += 64 * 256) {
        float s = 0.f;
        for (int i = 0; i < GRAM_BLOCKS; ++i) s += gp[(size_t)i * 16384 + e];
        Gram[e] = s;
    }
    if (blockIdx.x == 0 && threadIdx.x < 128) {
        float s = 0.f;
        for (int i = 0; i < GRAM_BLOCKS; ++i) s += xp[(size_t)i * 128 + threadIdx.x];
        xsum[threadIdx.x] = s;
    }
}

// ---------------------------------------------------------------------------
// K1: analytic BN folding for conv1a (128 ch) and conv1b (256 ch)
// ---------------------------------------------------------------------------
__global__ __launch_bounds__(128)
void stats_ab_kernel(const float* __restrict__ Gram, const float* __restrict__ xsum,
                     const float* __restrict__ w1a, const float* __restrict__ g1a,
                     const float* __restrict__ be1a,
                     const float* __restrict__ w1b, const float* __restrict__ g1b,
                     const float* __restrict__ be1b,
                     float* __restrict__ alpha_a, float* __restrict__ beta_a,
                     float* __restrict__ alpha_b, float* __restrict__ beta_b)
{
    const int t = threadIdx.x;
    const int cc = blockIdx.x;
    const float invN = 1.f / (float)(BB * NVV);
    const bool isA = cc < 128;
    const int c = isA ? cc : cc - 128;
    const float* Wrow = isA ? (w1a + (size_t)c * 128) : (w1b + (size_t)c * 128);
    __shared__ float Wr[128];
    __shared__ float red[4];
    Wr[t] = Wrow[t];
    __syncthreads();
    float gi = 0.f;
    const float* Grow = Gram + (size_t)t * 128;
    for (int j = 0; j < 128; ++j) gi = fmaf(Grow[j], Wr[j], gi);
    float pi = Wr[t] * gi * invN;
    float qi = (xsum[t] * invN) * Wr[t];
    for (int off = 32; off > 0; off >>= 1) {
        pi += __shfl_down(pi, off);
        qi += __shfl_down(qi, off);
    }
    const int wid = t >> 6;
    if ((t & 63) == 0) { red[wid] = pi; red[2 + wid] = qi; }
    __syncthreads();
    if (t == 0) {
        const float P = red[0] + red[1], Q = red[2] + red[3];
        const float var = P - Q * Q;
        const float g = isA ? g1a[c] : g1b[c];
        const float be = isA ? be1a[c] : be1b[c];
        const float a = g * rsqrtf(var + EPSBN);
        if (isA) { alpha_a[c] = a; beta_a[c] = be - a * Q; }
        else     { alpha_b[c] = a; beta_b[c] = be - a * Q; }
    }
}

// ---------------------------------------------------------------------------
// MFMA conv: A = activations [B][NV][128] bf16 (verts = rows),
//            B = weights (fp32 -> bf16 on stage), 128x128 out tile per block.
// MODE 0: Asrc=xT. z=0: W=w1a -> h = relu(aA*dot+bA), bf16 [B][NV][128].
//                 z=1,2: W=w1b rows (z-1)*128.. -> x2 = aB*dot+bB, bf16 [B][256][NV].
// MODE 1: Asrc=meshraw with BN2+relu on staging; W=w3a rows z*128..;
//         raw dot -> d_out fp32 [B][256][NV] + channel stats partials.
// ---------------------------------------------------------------------------
template <int MODE>
__global__ __launch_bounds__(256)
void mfma_conv_kernel(const ushort* __restrict__ Asrc,
                      const float* __restrict__ Wa, const float* __restrict__ Wb,
                      const float* __restrict__ aIn, const float* __restrict__ bIn,
                      const float* __restrict__ aA, const float* __restrict__ bA,
                      const float* __restrict__ aB, const float* __restrict__ bB,
                      ushort* __restrict__ hOut, ushort* __restrict__ x2Out,
                      float* __restrict__ fOut,
                      float* __restrict__ statSum, float* __restrict__ statSsq)
{
    __shared__ __align__(16) ushort As[128 * 64];
    __shared__ __align__(16) ushort Bs[128 * 64];
    __shared__ float aS[128], bS[128];
    __shared__ float statS[256], statQ[256];
    const int t = threadIdx.x;
    const int vblk = blockIdx.x, b = blockIdx.y, z = blockIdx.z;
    const int v0 = vblk * 128;
    const int l = t & 63, wid = t >> 6;
    const int wr = wid >> 1, wc = wid & 1;
    const int l15 = l & 15, l4 = l >> 4;

    const float* W;
    if (MODE == 0) W = (z == 0) ? Wa : (Wb + (size_t)(z - 1) * 128 * 128);
    else           W = Wa + (size_t)z * 128 * 128;
    if (t < 128) {
        if (MODE == 1)      { aS[t] = aIn[t]; bS[t] = bIn[t]; }
        else if (z == 0)    { aS[t] = aA[t];  bS[t] = bA[t]; }
        else                { aS[t] = aB[(z - 1) * 128 + t]; bS[t] = bB[(z - 1) * 128 + t]; }
    }
    __syncthreads();

    f32x4_t acc[4][4];
#pragma unroll
    for (int m = 0; m < 4; ++m)
#pragma unroll
        for (int n = 0; n < 4; ++n) acc[m][n] = (f32x4_t){0.f, 0.f, 0.f, 0.f};

    for (int kc = 0; kc < 128; kc += 64) {
        // stage A (activations)
#pragma unroll
        for (int i = 0; i < 4; ++i) {
            const int item = t + (i << 8);
            const int r = item >> 3, piece = item & 7;
            const int cb = kc + piece * 8;
            const int v = v0 + r;
            uint4 pk = make_uint4(0u, 0u, 0u, 0u);
            if (v < NVV) {
                pk = *reinterpret_cast<const uint4*>(Asrc + ((size_t)b * NVV + v) * 128 + cb);
                if (MODE == 1) {
                    float s[8];
                    unpack2(pk.x, s[0], s[1]); unpack2(pk.y, s[2], s[3]);
                    unpack2(pk.z, s[4], s[5]); unpack2(pk.w, s[6], s[7]);
#pragma unroll
                    for (int e = 0; e < 8; ++e)
                        s[e] = fmaxf(fmaf(aS[cb + e], s[e], bS[cb + e]), 0.f);
                    pk = pack8(s);
                }
            }
            const int byte = (r << 7) + (piece << 4);
            *reinterpret_cast<uint4*>((char*)As + (byte ^ ((r & 7) << 4))) = pk;
        }
        // stage B (weights fp32 -> bf16)
#pragma unroll
        for (int i = 0; i < 16; ++i) {
            const int idx = t + (i << 8);
            const int o = idx >> 5, kp = idx & 31;
            const float2 wv = *reinterpret_cast<const float2*>(&W[(size_t)o * 128 + kc + 2 * kp]);
            const int byte = (o << 7) + (kp << 2);
            *reinterpret_cast<uint*>((char*)Bs + (byte ^ ((o & 7) << 4))) = pack2(wv.x, wv.y);
        }
        __syncthreads();
#pragma unroll
        for (int kk2 = 0; kk2 < 2; ++kk2) {
            bf16x8_t af[4], bfr[4];
#pragma unroll
            for (int m = 0; m < 4; ++m) {
                const int row = wr * 64 + m * 16 + l15;
                const int byte = (row << 7) + (kk2 << 6) + (l4 << 4);
                af[m] = *reinterpret_cast<const bf16x8_t*>((const char*)As + (byte ^ ((row & 7) << 4)));
            }
#pragma unroll
            for (int n = 0; n < 4; ++n) {
                const int o = wc * 64 + n * 16 + l15;
                const int byte = (o << 7) + (kk2 << 6) + (l4 << 4);
                bfr[n] = *reinterpret_cast<const bf16x8_t*>((const char*)Bs + (byte ^ ((o & 7) << 4)));
            }
#pragma unroll
            for (int m = 0; m < 4; ++m)
#pragma unroll
                for (int n = 0; n < 4; ++n)
                    acc[m][n] = __builtin_amdgcn_mfma_f32_16x16x32_bf16(af[m], bfr[n], acc[m][n], 0, 0, 0);
        }
        __syncthreads();
    }

    if (MODE == 0 && z == 0) {
        // h[b][v][c] = relu(aS*dot+bS)
#pragma unroll
        for (int m = 0; m < 4; ++m) {
#pragma unroll
            for (int j = 0; j < 4; ++j) {
                const int v = v0 + wr * 64 + m * 16 + l4 * 4 + j;
                if (v < NVV) {
                    ushort* mp = hOut + ((size_t)b * NVV + v) * 128 + wc * 64 + l15;
#pragma unroll
                    for (int n = 0; n < 4; ++n) {
                        const int c = wc * 64 + n * 16 + l15;
                        mp[n * 16] = f2bf(fmaxf(fmaf(aS[c], acc[m][n][j], bS[c]), 0.f));
                    }
                }
            }
        }
    } else if (MODE == 0) {
        // x2[b][ch][v]
#pragma unroll
        for (int m = 0; m < 4; ++m) {
            const int vbase = v0 + wr * 64 + m * 16 + l4 * 4;
#pragma unroll
            for (int n = 0; n < 4; ++n) {
                const int cl = wc * 64 + n * 16 + l15;
                const int ch = (z - 1) * 128 + cl;
                ushort* p = x2Out + ((size_t)b * 256 + ch) * NVV + vbase;
#pragma unroll
                for (int j = 0; j < 4; ++j)
                    if (vbase + j < NVV)
                        p[j] = f2bf(fmaf(aS[cl], acc[m][n][j], bS[cl]));
            }
        }
    } else {
        float ss[4] = {0.f, 0.f, 0.f, 0.f}, sq[4] = {0.f, 0.f, 0.f, 0.f};
#pragma unroll
        for (int m = 0; m < 4; ++m) {
            const int vbase = v0 + wr * 64 + m * 16 + l4 * 4;
#pragma unroll
            for (int n = 0; n < 4; ++n) {
                const int cl = wc * 64 + n * 16 + l15;
                const int ch = z * 128 + cl;
                float* p = fOut + ((size_t)b * 256 + ch) * NVV + vbase;
#pragma unroll
                for (int j = 0; j < 4; ++j) {
                    if (vbase + j < NVV) {
                        const float val = acc[m][n][j];
                        p[j] = val;
                        ss[n] += val;
                        sq[n] = fmaf(val, val, sq[n]);
                    }
                }
            }
        }
#pragma unroll
        for (int n = 0; n < 4; ++n) {
            ss[n] += __shfl_xor(ss[n], 16); ss[n] += __shfl_xor(ss[n], 32);
            sq[n] += __shfl_xor(sq[n], 16); sq[n] += __shfl_xor(sq[n], 32);
        }
        if (l < 16) {
#pragma unroll
            for (int n = 0; n < 4; ++n) {
                statS[wr * 128 + wc * 64 + n * 16 + l] = ss[n];
                statQ[wr * 128 + wc * 64 + n * 16 + l] = sq[n];
            }
        }
        __syncthreads();
        if (t < 128) {
            const int slot = b * 81 + vblk;
            statSum[((size_t)z * 648 + slot) * 128 + t] = statS[t] + statS[128 + t];
            statSsq[((size_t)z * 648 + slot) * 128 + t] = statQ[t] + statQ[128 + t];
        }
    }
}

// ---------------------------------------------------------------------------
// Face kernel: gf_ew/gf_ns per face from h.  gf [B][NF][2][128] bf16.
// ---------------------------------------------------------------------------
__global__ __launch_bounds__(256)
void face_kernel(const ushort* __restrict__ h, const float* __restrict__ Gv,
                 const int* __restrict__ Gc, const float* __restrict__ EW,
                 const float* __restrict__ NSm, ushort* __restrict__ gf)
{
    const int t = threadIdx.x;
    const int lane = t & 63, wid = t >> 6;
    const int f = blockIdx.x * 4 + wid;
    const int b = blockIdx.y;
    const uint* hb = (const uint*)h + (size_t)b * NVV * 64;
    float ewx = 0.f, ewy = 0.f, nsx = 0.f, nsy = 0.f;
#pragma unroll
    for (int e = 0; e < 3; ++e) {
        const size_t r3 = ((size_t)e * NFF + f) * 3;
        float gx = 0.f, gy = 0.f;
#pragma unroll
        for (int j = 0; j < 3; ++j) {
            const float w = Gv[r3 + j];
            const int col = Gc[r3 + j];
            const uint hv = hb[(size_t)col * 64 + lane];
            float lo, hi; unpack2(hv, lo, hi);
            gx = fmaf(w, lo, gx); gy = fmaf(w, hi, gy);
        }
        const float we = EW[f * 3 + e], wn = NSm[f * 3 + e];
        ewx = fmaf(we, gx, ewx); ewy = fmaf(we, gy, ewy);
        nsx = fmaf(wn, gx, nsx); nsy = fmaf(wn, gy, nsy);
    }
    uint* go = (uint*)gf + ((size_t)b * NFF + f) * 128;
    go[lane]      = pack2(ewx, ewy);
    go[64 + lane] = pack2(nsx, nsy);
}

// ---------------------------------------------------------------------------
// Prepack coeffs into the exact swizzled LDS image (8 chunks x 4096 uints)
// ---------------------------------------------------------------------------
__global__ __launch_bounds__(256)
void prepack_coeffs_kernel(const float* __restrict__ coeffs, uint* __restrict__ cpk)
{
    const int j = blockIdx.x * 256 + threadIdx.x;      // 0..32767
    const int chunk = j >> 12, u = j & 4095;
    const int o = u >> 5;
    const int inner = (u << 2) & 127;
    const int inner0 = inner ^ ((o & 7) << 4);
    const int p = inner0 >> 2;
    const int q = chunk >> 1, c0 = (chunk & 1) << 6;
    const int row0 = (c0 + 2 * p) * 4 + q;
    cpk[j] = pack2(coeffs[(size_t)row0 * 128 + o], coeffs[(size_t)(row0 + 4) * 128 + o]);
}

// ---------------------------------------------------------------------------
// mesh_gemm: 512 threads, 8 waves. Per block 128 vertex rows. L/F indices
// staged in LDS once; coeffs chunks copied from prepacked image.
// ---------------------------------------------------------------------------
__global__ __launch_bounds__(512)
void mesh_gemm_kernel(const ushort* __restrict__ h, const ushort* __restrict__ gf,
                      const uint4* __restrict__ cpk,
                      const float* __restrict__ Lv, const int* __restrict__ Lc,
                      const float* __restrict__ Fv, const int* __restrict__ Fc,
                      ushort* __restrict__ meshraw,
                      float* __restrict__ msum, float* __restrict__ mssq)
{
    __shared__ __align__(16) ushort As[128 * 64];
    __shared__ __align__(16) ushort Bs[128 * 64];
    __shared__ float statS[512], statQ[512];
    __shared__ int   LciS[896];
    __shared__ float LwS[896];
    __shared__ int   FciS[768];
    __shared__ float FwS[768];
    const int t = threadIdx.x;
    const int b = blockIdx.y;
    const int v0 = blockIdx.x * 128;
    const int l = t & 63, wid = t >> 6;
    const int wr = wid >> 1, wc = wid & 1;
    const int l15 = l & 15, l4 = l >> 4;
    const size_t hb = (size_t)b * NVV * 128;

    for (int i = t; i < 896; i += 512) {
        const int g = v0 * 7 + i;
        if (g < NVV * 7) { LciS[i] = Lc[g]; LwS[i] = Lv[g]; }
    }
    for (int i = t; i < 768; i += 512) {
        const int g = v0 * 6 + i;
        if (g < NVV * 6) { FciS[i] = Fc[g]; FwS[i] = Fv[g]; }
    }
    __syncthreads();

    f32x4_t acc[2][4];
#pragma unroll
    for (int m = 0; m < 2; ++m)
#pragma unroll
        for (int n = 0; n < 4; ++n) acc[m][n] = (f32x4_t){0.f, 0.f, 0.f, 0.f};

    for (int chunk = 0; chunk < 8; ++chunk) {
        const int q = chunk >> 1, c0 = (chunk & 1) << 6;
#pragma unroll
        for (int i = 0; i < 2; ++i) {
            const int item = t + (i << 9);
            const int r = item >> 3, piece = item & 7;
            const int cb = c0 + piece * 8;
            const int v = v0 + r;
            uint4 pk = make_uint4(0u, 0u, 0u, 0u);
            if (v < NVV) {
                if (q == 0) {
                    pk = *reinterpret_cast<const uint4*>(h + hb + (size_t)v * 128 + cb);
                } else if (q == 1) {
                    float s[8] = {0.f, 0.f, 0.f, 0.f, 0.f, 0.f, 0.f, 0.f};
#pragma unroll
                    for (int j = 0; j < 7; ++j) {
                        const float w = LwS[r * 7 + j];
                        const int col = LciS[r * 7 + j];
                        const uint4 hv = *reinterpret_cast<const uint4*>(h + hb + (size_t)col * 128 + cb);
                        fma8(hv, w, s);
                    }
                    pk = pack8(s);
                } else {
                    const int slab = q - 2;
                    float s[8] = {0.f, 0.f, 0.f, 0.f, 0.f, 0.f, 0.f, 0.f};
#pragma unroll
                    for (int j = 0; j < 6; ++j) {
                        const float w = FwS[r * 6 + j];
                        const int f = FciS[r * 6 + j];
                        const uint4 gv = *reinterpret_cast<const uint4*>(
                            gf + (((size_t)b * NFF + f) * 2 + slab) * 128 + cb);
                        fma8(gv, w, s);
                    }
                    pk = pack8(s);
                }
            }
            const int byte = (r << 7) + (piece << 4);
            *reinterpret_cast<uint4*>((char*)As + (byte ^ ((r & 7) << 4))) = pk;
        }
        // stage B: straight copy of prepacked swizzled image (conflict-free)
#pragma unroll
        for (int i = 0; i < 2; ++i) {
            const int idx = t + (i << 9);
            reinterpret_cast<uint4*>(Bs)[idx] = cpk[chunk * 1024 + idx];
        }
        __syncthreads();
#pragma unroll
        for (int kk2 = 0; kk2 < 2; ++kk2) {
            bf16x8_t af[2], bfr[4];
#pragma unroll
            for (int m = 0; m < 2; ++m) {
                const int row = wr * 32 + m * 16 + l15;
                const int byte = (row << 7) + (kk2 << 6) + (l4 << 4);
                af[m] = *reinterpret_cast<const bf16x8_t*>((const char*)As + (byte ^ ((row & 7) << 4)));
            }
#pragma unroll
            for (int n = 0; n < 4; ++n) {
                const int o = wc * 64 + n * 16 + l15;
                const int byte = (o << 7) + (kk2 << 6) + (l4 << 4);
                bfr[n] = *reinterpret_cast<const bf16x8_t*>((const char*)Bs + (byte ^ ((o & 7) << 4)));
            }
#pragma unroll
            for (int m = 0; m < 2; ++m)
#pragma unroll
                for (int n = 0; n < 4; ++n)
                    acc[m][n] = __builtin_amdgcn_mfma_f32_16x16x32_bf16(af[m], bfr[n], acc[m][n], 0, 0, 0);
        }
        __syncthreads();
    }
    // epilogue: meshraw bf16 + stats
    float ss[4] = {0.f, 0.f, 0.f, 0.f}, sq[4] = {0.f, 0.f, 0.f, 0.f};
#pragma unroll
    for (int m = 0; m < 2; ++m) {
#pragma unroll
        for (int j = 0; j < 4; ++j) {
            const int row = wr * 32 + m * 16 + l4 * 4 + j;
            const int v = v0 + row;
            if (v < NVV) {
                ushort* mp = meshraw + hb + (size_t)v * 128 + wc * 64 + l15;
#pragma unroll
                for (int n = 0; n < 4; ++n) {
                    const float val = acc[m][n][j];
                    mp[n * 16] = f2bf(val);
                    ss[n] += val;
                    sq[n] = fmaf(val, val, sq[n]);
                }
            }
        }
    }
#pragma unroll
    for (int n = 0; n < 4; ++n) {
        ss[n] += __shfl_xor(ss[n], 16); ss[n] += __shfl_xor(ss[n], 32);
        sq[n] += __shfl_xor(sq[n], 16); sq[n] += __shfl_xor(sq[n], 32);
    }
    if (l < 16) {
#pragma unroll
        for (int n = 0; n < 4; ++n) {
            statS[wr * 128 + wc * 64 + n * 16 + l] = ss[n];
            statQ[wr * 128 + wc * 64 + n * 16 + l] = sq[n];
        }
    }
    __syncthreads();
    if (t < 128) {
        const int blk = b * 81 + blockIdx.x;
        msum[(size_t)blk * 128 + t] = statS[t] + statS[128 + t] + statS[256 + t] + statS[384 + t];
        mssq[(size_t)blk * 128 + t] = statQ[t] + statQ[128 + t] + statQ[256 + t] + statQ[384 + t];
    }
}

// ---------------------------------------------------------------------------
__global__ __launch_bounds__(256)
void finalize_stats_kernel(const float* __restrict__ s, const float* __restrict__ q, int count,
                           const float* __restrict__ g, const float* __restrict__ be,
                           float* __restrict__ alpha, float* __restrict__ beta, int split)
{
    const int c = blockIdx.x, t = threadIdx.x;
    const size_t base = split ? ((size_t)(c >> 7) * count * 128 + (c & 127)) : (size_t)c;
    float ls = 0.f, lq = 0.f;
    for (int i = t; i < count; i += 256) {
        ls += s[base + (size_t)i * 128];
        lq += q[base + (size_t)i * 128];
    }
    __shared__ float rs[256], rq[256];
    rs[t] = ls; rq[t] = lq;
    __syncthreads();
    for (int off = 128; off > 0; off >>= 1) {
        if (t < off) { rs[t] += rs[t + off]; rq[t] += rq[t + off]; }
        __syncthreads();
    }
    if (t == 0) {
        const float invN = 1.f / (float)(BB * NVV);
        const float mean = rs[0] * invN;
        const float var = rq[0] * invN - mean * mean;
        const float a = g[c] * rsqrtf(var + EPSBN);
        alpha[c] = a;
        beta[c] = be[c] - a * mean;
    }
}

// ---------------------------------------------------------------------------
__global__ __launch_bounds__(256)
void final_kernel(float* __restrict__ out, const ushort* __restrict__ x2,
                  const float* __restrict__ alpha3, const float* __restrict__ beta3)
{
    const int blk = blockIdx.x;
    const int o = blk & 255;
    const float a = alpha3[o], bb = beta3[o];
    float2* po = reinterpret_cast<float2*>(out + (size_t)blk * NVV);
    const uint* p2 = reinterpret_cast<const uint*>(x2 + (size_t)blk * NVV);
    for (int i = threadIdx.x; i < NVV / 2; i += 256) {
        const float2 v1 = po[i];
        float lo, hi; unpack2(p2[i], lo, hi);
        po[i] = make_float2(fmaxf(fmaf(a, v1.x, bb) + lo, 0.f),
                            fmaxf(fmaf(a, v1.y, bb) + hi, 0.f));
    }
}

// ---------------------------------------------------------------------------
extern "C" void kernel_launch(void* const* d_in, const int* in_sizes, int n_in,
                              void* d_out, int out_size, void* d_ws, size_t ws_size,
                              hipStream_t stream)
{
    (void)in_sizes; (void)n_in; (void)out_size;
    const float* x      = (const float*)d_in[0];
    const float* w1a    = (const float*)d_in[1];
    const float* g1a    = (const float*)d_in[3];
    const float* be1a   = (const float*)d_in[4];
    const float* coeffs = (const float*)d_in[5];
    const float* g2a    = (const float*)d_in[6];
    const float* be2a   = (const float*)d_in[7];
    const float* w3a    = (const float*)d_in[8];
    const float* g3a    = (const float*)d_in[10];
    const float* be3a   = (const float*)d_in[11];
    const float* w1b    = (const float*)d_in[12];
    const float* g1b    = (const float*)d_in[14];
    const float* be1b   = (const float*)d_in[15];
    const float* Gv     = (const float*)d_in[16];
    const float* Lv     = (const float*)d_in[17];
    const float* Fv     = (const float*)d_in[18];
    const float* EW     = (const float*)d_in[19];
    const float* NSm    = (const float*)d_in[20];
    const int*   Gc     = (const int*)d_in[22];
    const int*   Lc     = (const int*)d_in[24];
    const int*   Fc     = (const int*)d_in[26];

    char* base = (char*)d_ws;
    size_t off = 0;
    auto alloc = [&](size_t bytes) { char* p = base + off; off += (bytes + 255) & ~(size_t)255; return p; };

    // region0: gramPart+xsumPart (early) aliased with gf (late)
    const size_t gfBytes = (size_t)BB * NFF * 2 * 128 * 2;       // 83.9 MB
    char* region0   = alloc(gfBytes);
    float* gramPart = (float*)region0;
    float* xsumPart = (float*)(region0 + (size_t)GRAM_BLOCKS * 16384 * 4);
    ushort* gf      = (ushort*)region0;

    ushort* xT      = (ushort*)alloc((size_t)BB * NVV * 128 * 2);
    ushort* h       = (ushort*)alloc((size_t)BB * NVV * 128 * 2);
    ushort* meshraw = (ushort*)alloc((size_t)BB * NVV * 128 * 2);
    ushort* x2      = (ushort*)alloc((size_t)BB * 256 * NVV * 2);
    uint*  cpk      = (uint*)alloc(32768 * 4);
    float* Gram     = (float*)alloc(16384 * 4);
    float* xsum     = (float*)alloc(128 * 4);
    float* alpha_a  = (float*)alloc(128 * 4);
    float* beta_a   = (float*)alloc(128 * 4);
    float* alpha_b  = (float*)alloc(256 * 4);
    float* beta_b   = (float*)alloc(256 * 4);
    float* alpha2   = (float*)alloc(128 * 4);
    float* beta2    = (float*)alloc(128 * 4);
    float* alpha3   = (float*)alloc(256 * 4);
    float* beta3    = (float*)alloc(256 * 4);
    float* msum     = (float*)alloc((size_t)648 * 128 * 4);
    float* mssq     = (float*)alloc((size_t)648 * 128 * 4);
    float* x1sum    = (float*)alloc((size_t)2 * 648 * 128 * 4);
    float* x1ssq    = (float*)alloc((size_t)2 * 648 * 128 * 4);
    if (off > ws_size) return;   // fail loud (validation will catch)

    gram_kernel<<<GRAM_BLOCKS, 256, 0, stream>>>(x, gramPart, xsumPart, (uint*)xT);
    reduce_gram_kernel<<<64, 256, 0, stream>>>(gramPart, xsumPart, Gram, xsum);
    stats_ab_kernel<<<384, 128, 0, stream>>>(Gram, xsum, w1a, g1a, be1a, w1b, g1b, be1b,
                                             alpha_a, beta_a, alpha_b, beta_b);
    prepack_coeffs_kernel<<<128, 256, 0, stream>>>(coeffs, cpk);
    mfma_conv_kernel<0><<<dim3(81, 8, 3), 256, 0, stream>>>(
        xT, w1a, w1b, nullptr, nullptr, alpha_a, beta_a, alpha_b, beta_b,
        h, x2, nullptr, nullptr, nullptr);
    face_kernel<<<dim3(NFF / 4, 8), 256, 0, stream>>>(h, Gv, Gc, EW, NSm, gf);
    mesh_gemm_kernel<<<dim3(81, 8), 512, 0, stream>>>(h, gf, (const uint4*)cpk,
                                                      Lv, Lc, Fv, Fc, meshraw, msum, mssq);
    finalize_stats_kernel<<<128, 256, 0, stream>>>(msum, mssq, 648, g2a, be2a, alpha2, beta2, 0);
    mfma_conv_kernel<1><<<dim3(81, 8, 2), 256, 0, stream>>>(
        meshraw, w3a, nullptr, alpha2, beta2, nullptr, nullptr, nullptr, nullptr,
        nullptr, nullptr, (float*)d_out, x1sum, x1ssq);
    finalize_stats_kernel<<<256, 256, 0, stream>>>(x1sum, x1ssq, 648, g3a, be3a, alpha3, beta3, 1);
    final_kernel<<<2048, 256, 0, stream>>>((float*)d_out, x2, alpha3, beta3);
}

// Round 4
// 362.834 us; speedup vs baseline: 3.8218x; 1.2237x over previous
//
#include <hip/hip_runtime.h>
#include <math.h>

#define BB   8
#define NVV  10242
#define NFF  20480
#define EPSBN 1e-5f
#define GRAM_BLOCKS 644   // x 2 chunks each = 1288 = 8 batches * 161 vert-chunks

typedef __attribute__((ext_vector_type(8))) short bf16x8_t;
typedef __attribute__((ext_vector_type(4))) float f32x4_t;

__device__ inline float bf2f(ushort u) {
    union { uint i; float f; } v; v.i = ((uint)u) << 16; return v.f;
}
__device__ inline ushort f2bf(float f) {
    union { float f; uint i; } v; v.f = f;
    const uint r = v.i + 0x7fffu + ((v.i >> 16) & 1u);
    return (ushort)(r >> 16);
}
__device__ inline void unpack2(uint w, float& lo, float& hi) {
    union { uint i; float f; } a, b;
    a.i = w << 16; b.i = w & 0xffff0000u;
    lo = a.f; hi = b.f;
}
__device__ inline uint pack2(float lo, float hi) {
    return (uint)f2bf(lo) | ((uint)f2bf(hi) << 16);
}
__device__ inline void fma8(const uint4 hv, const float w, float s[8]) {
    float lo, hi;
    unpack2(hv.x, lo, hi); s[0] = fmaf(w, lo, s[0]); s[1] = fmaf(w, hi, s[1]);
    unpack2(hv.y, lo, hi); s[2] = fmaf(w, lo, s[2]); s[3] = fmaf(w, hi, s[3]);
    unpack2(hv.z, lo, hi); s[4] = fmaf(w, lo, s[4]); s[5] = fmaf(w, hi, s[5]);
    unpack2(hv.w, lo, hi); s[6] = fmaf(w, lo, s[6]); s[7] = fmaf(w, hi, s[7]);
}
__device__ inline uint4 pack8(const float s[8]) {
    uint4 p;
    p.x = pack2(s[0], s[1]); p.y = pack2(s[2], s[3]);
    p.z = pack2(s[4], s[5]); p.w = pack2(s[6], s[7]);
    return p;
}

// ---------------------------------------------------------------------------
// K0: Gram partials via MFMA bf16 hi/lo split + xsum partials + xT bf16 write.
// Gram = X X^T over 8*10242 samples; X split x = hi + lo (bf16 each),
// Gram ~= hi.hi^T + hi.lo^T + lo.hi^T  (fp32 accum; lo.lo ~ 2^-18 dropped).
// Block: 256 thr / 4 waves; 2 chunks of 64 verts; wave computes 32x128 slab.
// ---------------------------------------------------------------------------
__global__ __launch_bounds__(256)
void gram_kernel(const float* __restrict__ x, float* __restrict__ gramPart,
                 float* __restrict__ xsumPart, uint* __restrict__ xTu)
{
    __shared__ __align__(16) ushort Ahi[128 * 64];
    __shared__ __align__(16) ushort Alo[128 * 64];
    const int t = threadIdx.x;
    const int l = t & 63, wid = t >> 6;
    const int l15 = l & 15, l4 = l >> 4;
    f32x4_t acc[2][8];
#pragma unroll
    for (int m = 0; m < 2; ++m)
#pragma unroll
        for (int n = 0; n < 8; ++n) acc[m][n] = (f32x4_t){0.f, 0.f, 0.f, 0.f};
    float xs[8] = {0.f, 0.f, 0.f, 0.f, 0.f, 0.f, 0.f, 0.f};

    for (int s = 0; s < 2; ++s) {
        const int cc = blockIdx.x * 2 + s;
        const int b = cc / 161, tb = cc % 161, v0 = tb * 64;
        // ---- stage: load fp32, split hi/lo bf16, accumulate column sums ----
#pragma unroll
        for (int i = 0; i < 8; ++i) {
            const int item = t + (i << 8);
            const int c = item >> 4, vq = item & 15;
            const int gv = v0 + (vq << 2);
            const float* xp = x + ((size_t)b * 128 + c) * NVV + gv;
            float4 xv = make_float4(0.f, 0.f, 0.f, 0.f);
            if (gv + 4 <= NVV) {
                xv = *reinterpret_cast<const float4*>(xp);
            } else {
                if (gv     < NVV) xv.x = xp[0];
                if (gv + 1 < NVV) xv.y = xp[1];
            }
            xs[i] += xv.x + xv.y + xv.z + xv.w;
            const ushort h0 = f2bf(xv.x), h1 = f2bf(xv.y), h2 = f2bf(xv.z), h3 = f2bf(xv.w);
            const ushort e0 = f2bf(xv.x - bf2f(h0)), e1 = f2bf(xv.y - bf2f(h1));
            const ushort e2 = f2bf(xv.z - bf2f(h2)), e3 = f2bf(xv.w - bf2f(h3));
            uint2 hp, lp;
            hp.x = (uint)h0 | ((uint)h1 << 16); hp.y = (uint)h2 | ((uint)h3 << 16);
            lp.x = (uint)e0 | ((uint)e1 << 16); lp.y = (uint)e2 | ((uint)e3 << 16);
            const int byte = (c << 7) + (vq << 3);
            const int swz = byte ^ ((c & 7) << 4);
            *reinterpret_cast<uint2*>((char*)Ahi + swz) = hp;
            *reinterpret_cast<uint2*>((char*)Alo + swz) = lp;
        }
        __syncthreads();
        // ---- xT write (transpose of hi tile; lanes=verts -> ~2-way banks) ----
        {
            const int v = t & 63, cq = t >> 6;
            const int gv = v0 + v;
            if (gv < NVV) {
                uint4* rowp = reinterpret_cast<uint4*>(xTu + ((size_t)b * NVV + gv) * 64) + (cq << 2);
#pragma unroll
                for (int k2 = 0; k2 < 4; ++k2) {
                    uint wrd[4];
#pragma unroll
                    for (int w2 = 0; w2 < 4; ++w2) {
                        const int c0 = (cq << 5) + (k2 << 3) + (w2 << 1);
                        const int b0 = ((c0) << 7) + (v << 1);
                        const int b1 = ((c0 + 1) << 7) + (v << 1);
                        const ushort q0 = *reinterpret_cast<const ushort*>((const char*)Ahi + (b0 ^ ((c0 & 7) << 4)));
                        const ushort q1 = *reinterpret_cast<const ushort*>((const char*)Ahi + (b1 ^ (((c0 + 1) & 7) << 4)));
                        wrd[w2] = (uint)q0 | ((uint)q1 << 16);
                    }
                    rowp[k2] = make_uint4(wrd[0], wrd[1], wrd[2], wrd[3]);
                }
            }
        }
        // ---- MFMA: wave slab rows wid*32..+31 vs all 128 cols ----
#pragma unroll
        for (int kk2 = 0; kk2 < 2; ++kk2) {
            bf16x8_t ah[2], al[2];
#pragma unroll
            for (int m = 0; m < 2; ++m) {
                const int row = wid * 32 + m * 16 + l15;
                const int byte = (row << 7) + (kk2 << 6) + (l4 << 4);
                ah[m] = *reinterpret_cast<const bf16x8_t*>((const char*)Ahi + (byte ^ ((row & 7) << 4)));
                al[m] = *reinterpret_cast<const bf16x8_t*>((const char*)Alo + (byte ^ ((row & 7) << 4)));
            }
#pragma unroll
            for (int n = 0; n < 8; ++n) {
                const int rn = n * 16 + l15;
                const int byte = (rn << 7) + (kk2 << 6) + (l4 << 4);
                const bf16x8_t bh = *reinterpret_cast<const bf16x8_t*>((const char*)Ahi + (byte ^ ((rn & 7) << 4)));
                const bf16x8_t bl = *reinterpret_cast<const bf16x8_t*>((const char*)Alo + (byte ^ ((rn & 7) << 4)));
#pragma unroll
                for (int m = 0; m < 2; ++m) {
                    acc[m][n] = __builtin_amdgcn_mfma_f32_16x16x32_bf16(ah[m], bh, acc[m][n], 0, 0, 0);
                    acc[m][n] = __builtin_amdgcn_mfma_f32_16x16x32_bf16(ah[m], bl, acc[m][n], 0, 0, 0);
                    acc[m][n] = __builtin_amdgcn_mfma_f32_16x16x32_bf16(al[m], bh, acc[m][n], 0, 0, 0);
                }
            }
        }
        __syncthreads();
    }
    // ---- write Gram partial [128][128] ----
    float* gp = gramPart + (size_t)blockIdx.x * 16384;
#pragma unroll
    for (int m = 0; m < 2; ++m)
#pragma unroll
        for (int n = 0; n < 8; ++n)
#pragma unroll
            for (int j = 0; j < 4; ++j) {
                const int row = wid * 32 + m * 16 + l4 * 4 + j;
                const int col = n * 16 + l15;
                gp[row * 128 + col] = acc[m][n][j];
            }
    // ---- xsum partial: channel = wid*4 + (l>>4) + i*16, reduce over l&15 ----
#pragma unroll
    for (int i = 0; i < 8; ++i) {
        xs[i] += __shfl_xor(xs[i], 1);
        xs[i] += __shfl_xor(xs[i], 2);
        xs[i] += __shfl_xor(xs[i], 4);
        xs[i] += __shfl_xor(xs[i], 8);
    }
    if ((l & 15) == 0) {
#pragma unroll
        for (int i = 0; i < 8; ++i)
            xsumPart[(size_t)blockIdx.x * 128 + wid * 4 + l4 + i * 16] = xs[i];
    }
}

__global__ void reduce_gram_kernel(const float* __restrict__ gp, const float* __restrict__ xp,
                                   float* __restrict__ Gram, float* __restrict__ xsum)
{
    const int tid = blockIdx.x * 256 + threadIdx.x;
    for (int e = tid; e < 16384; e += 64 * 256) {
        float s = 0.f;
        for (int i = 0; i < GRAM_BLOCKS; ++i) s += gp[(size_t)i * 16384 + e];
        Gram[e] = s;
    }
    if (blockIdx.x == 0 && threadIdx.x < 128) {
        float s = 0.f;
        for (int i = 0; i < GRAM_BLOCKS; ++i) s += xp[(size_t)i * 128 + threadIdx.x];
        xsum[threadIdx.x] = s;
    }
}

// ---------------------------------------------------------------------------
// K1: analytic BN folding for conv1a (128 ch) and conv1b (256 ch)
// ---------------------------------------------------------------------------
__global__ __launch_bounds__(128)
void stats_ab_kernel(const float* __restrict__ Gram, const float* __restrict__ xsum,
                     const float* __restrict__ w1a, const float* __restrict__ g1a,
                     const float* __restrict__ be1a,
                     const float* __restrict__ w1b, const float* __restrict__ g1b,
                     const float* __restrict__ be1b,
                     float* __restrict__ alpha_a, float* __restrict__ beta_a,
                     float* __restrict__ alpha_b, float* __restrict__ beta_b)
{
    const int t = threadIdx.x;
    const int cc = blockIdx.x;
    const float invN = 1.f / (float)(BB * NVV);
    const bool isA = cc < 128;
    const int c = isA ? cc : cc - 128;
    const float* Wrow = isA ? (w1a + (size_t)c * 128) : (w1b + (size_t)c * 128);
    __shared__ float Wr[128];
    __shared__ float red[4];
    Wr[t] = Wrow[t];
    __syncthreads();
    float gi = 0.f;
    const float* Grow = Gram + (size_t)t * 128;
    for (int j = 0; j < 128; ++j) gi = fmaf(Grow[j], Wr[j], gi);
    float pi = Wr[t] * gi * invN;
    float qi = (xsum[t] * invN) * Wr[t];
    for (int off = 32; off > 0; off >>= 1) {
        pi += __shfl_down(pi, off);
        qi += __shfl_down(qi, off);
    }
    const int wid = t >> 6;
    if ((t & 63) == 0) { red[wid] = pi; red[2 + wid] = qi; }
    __syncthreads();
    if (t == 0) {
        const float P = red[0] + red[1], Q = red[2] + red[3];
        const float var = P - Q * Q;
        const float g = isA ? g1a[c] : g1b[c];
        const float be = isA ? be1a[c] : be1b[c];
        const float a = g * rsqrtf(var + EPSBN);
        if (isA) { alpha_a[c] = a; beta_a[c] = be - a * Q; }
        else     { alpha_b[c] = a; beta_b[c] = be - a * Q; }
    }
}

// ---------------------------------------------------------------------------
// MFMA conv: A = activations [B][NV][128] bf16, B = weights fp32->bf16.
// MODE 0: Asrc=xT. z=0: h=relu(aA*dot+bA) bf16; z=1,2: x2=aB*dot+bB bf16.
// MODE 1: Asrc=meshraw (BN2+relu on staging); raw dot -> x1 bf16 + stats.
// ---------------------------------------------------------------------------
template <int MODE>
__global__ __launch_bounds__(256)
void mfma_conv_kernel(const ushort* __restrict__ Asrc,
                      const float* __restrict__ Wa, const float* __restrict__ Wb,
                      const float* __restrict__ aIn, const float* __restrict__ bIn,
                      const float* __restrict__ aA, const float* __restrict__ bA,
                      const float* __restrict__ aB, const float* __restrict__ bB,
                      ushort* __restrict__ hOut, ushort* __restrict__ x2Out,
                      ushort* __restrict__ x1Out,
                      float* __restrict__ statSum, float* __restrict__ statSsq)
{
    __shared__ __align__(16) ushort As[128 * 64];
    __shared__ __align__(16) ushort Bs[128 * 64];
    __shared__ float aS[128], bS[128];
    __shared__ float statS[256], statQ[256];
    const int t = threadIdx.x;
    const int vblk = blockIdx.x, b = blockIdx.y, z = blockIdx.z;
    const int v0 = vblk * 128;
    const int l = t & 63, wid = t >> 6;
    const int wr = wid >> 1, wc = wid & 1;
    const int l15 = l & 15, l4 = l >> 4;

    const float* W;
    if (MODE == 0) W = (z == 0) ? Wa : (Wb + (size_t)(z - 1) * 128 * 128);
    else           W = Wa + (size_t)z * 128 * 128;
    if (t < 128) {
        if (MODE == 1)      { aS[t] = aIn[t]; bS[t] = bIn[t]; }
        else if (z == 0)    { aS[t] = aA[t];  bS[t] = bA[t]; }
        else                { aS[t] = aB[(z - 1) * 128 + t]; bS[t] = bB[(z - 1) * 128 + t]; }
    }
    __syncthreads();

    f32x4_t acc[4][4];
#pragma unroll
    for (int m = 0; m < 4; ++m)
#pragma unroll
        for (int n = 0; n < 4; ++n) acc[m][n] = (f32x4_t){0.f, 0.f, 0.f, 0.f};

    for (int kc = 0; kc < 128; kc += 64) {
#pragma unroll
        for (int i = 0; i < 4; ++i) {
            const int item = t + (i << 8);
            const int r = item >> 3, piece = item & 7;
            const int cb = kc + piece * 8;
            const int v = v0 + r;
            uint4 pk = make_uint4(0u, 0u, 0u, 0u);
            if (v < NVV) {
                pk = *reinterpret_cast<const uint4*>(Asrc + ((size_t)b * NVV + v) * 128 + cb);
                if (MODE == 1) {
                    float s[8];
                    unpack2(pk.x, s[0], s[1]); unpack2(pk.y, s[2], s[3]);
                    unpack2(pk.z, s[4], s[5]); unpack2(pk.w, s[6], s[7]);
#pragma unroll
                    for (int e = 0; e < 8; ++e)
                        s[e] = fmaxf(fmaf(aS[cb + e], s[e], bS[cb + e]), 0.f);
                    pk = pack8(s);
                }
            }
            const int byte = (r << 7) + (piece << 4);
            *reinterpret_cast<uint4*>((char*)As + (byte ^ ((r & 7) << 4))) = pk;
        }
#pragma unroll
        for (int i = 0; i < 16; ++i) {
            const int idx = t + (i << 8);
            const int o = idx >> 5, kp = idx & 31;
            const float2 wv = *reinterpret_cast<const float2*>(&W[(size_t)o * 128 + kc + 2 * kp]);
            const int byte = (o << 7) + (kp << 2);
            *reinterpret_cast<uint*>((char*)Bs + (byte ^ ((o & 7) << 4))) = pack2(wv.x, wv.y);
        }
        __syncthreads();
#pragma unroll
        for (int kk2 = 0; kk2 < 2; ++kk2) {
            bf16x8_t af[4], bfr[4];
#pragma unroll
            for (int m = 0; m < 4; ++m) {
                const int row = wr * 64 + m * 16 + l15;
                const int byte = (row << 7) + (kk2 << 6) + (l4 << 4);
                af[m] = *reinterpret_cast<const bf16x8_t*>((const char*)As + (byte ^ ((row & 7) << 4)));
            }
#pragma unroll
            for (int n = 0; n < 4; ++n) {
                const int o = wc * 64 + n * 16 + l15;
                const int byte = (o << 7) + (kk2 << 6) + (l4 << 4);
                bfr[n] = *reinterpret_cast<const bf16x8_t*>((const char*)Bs + (byte ^ ((o & 7) << 4)));
            }
#pragma unroll
            for (int m = 0; m < 4; ++m)
#pragma unroll
                for (int n = 0; n < 4; ++n)
                    acc[m][n] = __builtin_amdgcn_mfma_f32_16x16x32_bf16(af[m], bfr[n], acc[m][n], 0, 0, 0);
        }
        __syncthreads();
    }

    if (MODE == 0 && z == 0) {
#pragma unroll
        for (int m = 0; m < 4; ++m) {
#pragma unroll
            for (int j = 0; j < 4; ++j) {
                const int v = v0 + wr * 64 + m * 16 + l4 * 4 + j;
                if (v < NVV) {
                    ushort* mp = hOut + ((size_t)b * NVV + v) * 128 + wc * 64 + l15;
#pragma unroll
                    for (int n = 0; n < 4; ++n) {
                        const int c = wc * 64 + n * 16 + l15;
                        mp[n * 16] = f2bf(fmaxf(fmaf(aS[c], acc[m][n][j], bS[c]), 0.f));
                    }
                }
            }
        }
    } else if (MODE == 0) {
#pragma unroll
        for (int m = 0; m < 4; ++m) {
            const int vbase = v0 + wr * 64 + m * 16 + l4 * 4;
#pragma unroll
            for (int n = 0; n < 4; ++n) {
                const int cl = wc * 64 + n * 16 + l15;
                const int ch = (z - 1) * 128 + cl;
                ushort* p = x2Out + ((size_t)b * 256 + ch) * NVV + vbase;
#pragma unroll
                for (int j = 0; j < 4; ++j)
                    if (vbase + j < NVV)
                        p[j] = f2bf(fmaf(aS[cl], acc[m][n][j], bS[cl]));
            }
        }
    } else {
        float ss[4] = {0.f, 0.f, 0.f, 0.f}, sq[4] = {0.f, 0.f, 0.f, 0.f};
#pragma unroll
        for (int m = 0; m < 4; ++m) {
            const int vbase = v0 + wr * 64 + m * 16 + l4 * 4;
#pragma unroll
            for (int n = 0; n < 4; ++n) {
                const int cl = wc * 64 + n * 16 + l15;
                const int ch = z * 128 + cl;
                ushort* p = x1Out + ((size_t)b * 256 + ch) * NVV + vbase;
#pragma unroll
                for (int j = 0; j < 4; ++j) {
                    if (vbase + j < NVV) {
                        const float val = acc[m][n][j];
                        p[j] = f2bf(val);
                        ss[n] += val;
                        sq[n] = fmaf(val, val, sq[n]);
                    }
                }
            }
        }
#pragma unroll
        for (int n = 0; n < 4; ++n) {
            ss[n] += __shfl_xor(ss[n], 16); ss[n] += __shfl_xor(ss[n], 32);
            sq[n] += __shfl_xor(sq[n], 16); sq[n] += __shfl_xor(sq[n], 32);
        }
        if (l < 16) {
#pragma unroll
            for (int n = 0; n < 4; ++n) {
                statS[wr * 128 + wc * 64 + n * 16 + l] = ss[n];
                statQ[wr * 128 + wc * 64 + n * 16 + l] = sq[n];
            }
        }
        __syncthreads();
        if (t < 128) {
            const int slot = b * 81 + vblk;
            statSum[((size_t)z * 648 + slot) * 128 + t] = statS[t] + statS[128 + t];
            statSsq[((size_t)z * 648 + slot) * 128 + t] = statQ[t] + statQ[128 + t];
        }
    }
}

// ---------------------------------------------------------------------------
// Face kernel: gf_ew/gf_ns per face from h.  gf [B][NF][2][128] bf16.
// ---------------------------------------------------------------------------
__global__ __launch_bounds__(256)
void face_kernel(const ushort* __restrict__ h, const float* __restrict__ Gv,
                 const int* __restrict__ Gc, const float* __restrict__ EW,
                 const float* __restrict__ NSm, ushort* __restrict__ gf)
{
    const int t = threadIdx.x;
    const int lane = t & 63, wid = t >> 6;
    const int f = blockIdx.x * 4 + wid;
    const int b = blockIdx.y;
    const uint* hb = (const uint*)h + (size_t)b * NVV * 64;
    float ewx = 0.f, ewy = 0.f, nsx = 0.f, nsy = 0.f;
#pragma unroll
    for (int e = 0; e < 3; ++e) {
        const size_t r3 = ((size_t)e * NFF + f) * 3;
        float gx = 0.f, gy = 0.f;
#pragma unroll
        for (int j = 0; j < 3; ++j) {
            const float w = Gv[r3 + j];
            const int col = Gc[r3 + j];
            const uint hv = hb[(size_t)col * 64 + lane];
            float lo, hi; unpack2(hv, lo, hi);
            gx = fmaf(w, lo, gx); gy = fmaf(w, hi, gy);
        }
        const float we = EW[f * 3 + e], wn = NSm[f * 3 + e];
        ewx = fmaf(we, gx, ewx); ewy = fmaf(we, gy, ewy);
        nsx = fmaf(wn, gx, nsx); nsy = fmaf(wn, gy, nsy);
    }
    uint* go = (uint*)gf + ((size_t)b * NFF + f) * 128;
    go[lane]      = pack2(ewx, ewy);
    go[64 + lane] = pack2(nsx, nsy);
}

// ---------------------------------------------------------------------------
// Prepack coeffs into the exact swizzled LDS image (8 chunks x 4096 uints)
// ---------------------------------------------------------------------------
__global__ __launch_bounds__(256)
void prepack_coeffs_kernel(const float* __restrict__ coeffs, uint* __restrict__ cpk)
{
    const int j = blockIdx.x * 256 + threadIdx.x;
    const int chunk = j >> 12, u = j & 4095;
    const int o = u >> 5;
    const int inner = (u << 2) & 127;
    const int inner0 = inner ^ ((o & 7) << 4);
    const int p = inner0 >> 2;
    const int q = chunk >> 1, c0 = (chunk & 1) << 6;
    const int row0 = (c0 + 2 * p) * 4 + q;
    cpk[j] = pack2(coeffs[(size_t)row0 * 128 + o], coeffs[(size_t)(row0 + 4) * 128 + o]);
}

// ---------------------------------------------------------------------------
// mesh_gemm: 512 threads, 8 waves; 128 vertex rows/block; L/F idx staged in LDS
// ---------------------------------------------------------------------------
__global__ __launch_bounds__(512)
void mesh_gemm_kernel(const ushort* __restrict__ h, const ushort* __restrict__ gf,
                      const uint4* __restrict__ cpk,
                      const float* __restrict__ Lv, const int* __restrict__ Lc,
                      const float* __restrict__ Fv, const int* __restrict__ Fc,
                      ushort* __restrict__ meshraw,
                      float* __restrict__ msum, float* __restrict__ mssq)
{
    __shared__ __align__(16) ushort As[128 * 64];
    __shared__ __align__(16) ushort Bs[128 * 64];
    __shared__ float statS[512], statQ[512];
    __shared__ int   LciS[896];
    __shared__ float LwS[896];
    __shared__ int   FciS[768];
    __shared__ float FwS[768];
    const int t = threadIdx.x;
    const int b = blockIdx.y;
    const int v0 = blockIdx.x * 128;
    const int l = t & 63, wid = t >> 6;
    const int wr = wid >> 1, wc = wid & 1;
    const int l15 = l & 15, l4 = l >> 4;
    const size_t hb = (size_t)b * NVV * 128;

    for (int i = t; i < 896; i += 512) {
        const int g = v0 * 7 + i;
        if (g < NVV * 7) { LciS[i] = Lc[g]; LwS[i] = Lv[g]; }
    }
    for (int i = t; i < 768; i += 512) {
        const int g = v0 * 6 + i;
        if (g < NVV * 6) { FciS[i] = Fc[g]; FwS[i] = Fv[g]; }
    }
    __syncthreads();

    f32x4_t acc[2][4];
#pragma unroll
    for (int m = 0; m < 2; ++m)
#pragma unroll
        for (int n = 0; n < 4; ++n) acc[m][n] = (f32x4_t){0.f, 0.f, 0.f, 0.f};

    for (int chunk = 0; chunk < 8; ++chunk) {
        const int q = chunk >> 1, c0 = (chunk & 1) << 6;
#pragma unroll
        for (int i = 0; i < 2; ++i) {
            const int item = t + (i << 9);
            const int r = item >> 3, piece = item & 7;
            const int cb = c0 + piece * 8;
            const int v = v0 + r;
            uint4 pk = make_uint4(0u, 0u, 0u, 0u);
            if (v < NVV) {
                if (q == 0) {
                    pk = *reinterpret_cast<const uint4*>(h + hb + (size_t)v * 128 + cb);
                } else if (q == 1) {
                    float s[8] = {0.f, 0.f, 0.f, 0.f, 0.f, 0.f, 0.f, 0.f};
#pragma unroll
                    for (int j = 0; j < 7; ++j) {
                        const float w = LwS[r * 7 + j];
                        const int col = LciS[r * 7 + j];
                        const uint4 hv = *reinterpret_cast<const uint4*>(h + hb + (size_t)col * 128 + cb);
                        fma8(hv, w, s);
                    }
                    pk = pack8(s);
                } else {
                    const int slab = q - 2;
                    float s[8] = {0.f, 0.f, 0.f, 0.f, 0.f, 0.f, 0.f, 0.f};
#pragma unroll
                    for (int j = 0; j < 6; ++j) {
                        const float w = FwS[r * 6 + j];
                        const int f = FciS[r * 6 + j];
                        const uint4 gv = *reinterpret_cast<const uint4*>(
                            gf + (((size_t)b * NFF + f) * 2 + slab) * 128 + cb);
                        fma8(gv, w, s);
                    }
                    pk = pack8(s);
                }
            }
            const int byte = (r << 7) + (piece << 4);
            *reinterpret_cast<uint4*>((char*)As + (byte ^ ((r & 7) << 4))) = pk;
        }
#pragma unroll
        for (int i = 0; i < 2; ++i) {
            const int idx = t + (i << 9);
            reinterpret_cast<uint4*>(Bs)[idx] = cpk[chunk * 1024 + idx];
        }
        __syncthreads();
#pragma unroll
        for (int kk2 = 0; kk2 < 2; ++kk2) {
            bf16x8_t af[2], bfr[4];
#pragma unroll
            for (int m = 0; m < 2; ++m) {
                const int row = wr * 32 + m * 16 + l15;
                const int byte = (row << 7) + (kk2 << 6) + (l4 << 4);
                af[m] = *reinterpret_cast<const bf16x8_t*>((const char*)As + (byte ^ ((row & 7) << 4)));
            }
#pragma unroll
            for (int n = 0; n < 4; ++n) {
                const int o = wc * 64 + n * 16 + l15;
                const int byte = (o << 7) + (kk2 << 6) + (l4 << 4);
                bfr[n] = *reinterpret_cast<const bf16x8_t*>((const char*)Bs + (byte ^ ((o & 7) << 4)));
            }
#pragma unroll
            for (int m = 0; m < 2; ++m)
#pragma unroll
                for (int n = 0; n < 4; ++n)
                    acc[m][n] = __builtin_amdgcn_mfma_f32_16x16x32_bf16(af[m], bfr[n], acc[m][n], 0, 0, 0);
        }
        __syncthreads();
    }
    float ss[4] = {0.f, 0.f, 0.f, 0.f}, sq[4] = {0.f, 0.f, 0.f, 0.f};
#pragma unroll
    for (int m = 0; m < 2; ++m) {
#pragma unroll
        for (int j = 0; j < 4; ++j) {
            const int row = wr * 32 + m * 16 + l4 * 4 + j;
            const int v = v0 + row;
            if (v < NVV) {
                ushort* mp = meshraw + hb + (size_t)v * 128 + wc * 64 + l15;
#pragma unroll
                for (int n = 0; n < 4; ++n) {
                    const float val = acc[m][n][j];
                    mp[n * 16] = f2bf(val);
                    ss[n] += val;
                    sq[n] = fmaf(val, val, sq[n]);
                }
            }
        }
    }
#pragma unroll
    for (int n = 0; n < 4; ++n) {
        ss[n] += __shfl_xor(ss[n], 16); ss[n] += __shfl_xor(ss[n], 32);
        sq[n] += __shfl_xor(sq[n], 16); sq[n] += __shfl_xor(sq[n], 32);
    }
    if (l < 16) {
#pragma unroll
        for (int n = 0; n < 4; ++n) {
            statS[wr * 128 + wc * 64 + n * 16 + l] = ss[n];
            statQ[wr * 128 + wc * 64 + n * 16 + l] = sq[n];
        }
    }
    __syncthreads();
    if (t < 128) {
        const int blk = b * 81 + blockIdx.x;
        msum[(size_t)blk * 128 + t] = statS[t] + statS[128 + t] + statS[256 + t] + statS[384 + t];
        mssq[(size_t)blk * 128 + t] = statQ[t] + statQ[128 + t] + statQ[256 + t] + statQ[384 + t];
    }
}

// ---------------------------------------------------------------------------
__global__ __launch_bounds__(256)
void finalize_stats_kernel(const float* __restrict__ s, const float* __restrict__ q, int count,
                           const float* __restrict__ g, const float* __restrict__ be,
                           float* __restrict__ alpha, float* __restrict__ beta, int split)
{
    const int c = blockIdx.x, t = threadIdx.x;
    const size_t base = split ? ((size_t)(c >> 7) * count * 128 + (c & 127)) : (size_t)c;
    float ls = 0.f, lq = 0.f;
    for (int i = t; i < count; i += 256) {
        ls += s[base + (size_t)i * 128];
        lq += q[base + (size_t)i * 128];
    }
    __shared__ float rs[256], rq[256];
    rs[t] = ls; rq[t] = lq;
    __syncthreads();
    for (int off = 128; off > 0; off >>= 1) {
        if (t < off) { rs[t] += rs[t + off]; rq[t] += rq[t + off]; }
        __syncthreads();
    }
    if (t == 0) {
        const float invN = 1.f / (float)(BB * NVV);
        const float mean = rs[0] * invN;
        const float var = rq[0] * invN - mean * mean;
        const float a = g[c] * rsqrtf(var + EPSBN);
        alpha[c] = a;
        beta[c] = be[c] - a * mean;
    }
}

// ---------------------------------------------------------------------------
// K8: out = relu(alpha3*x1 + beta3 + x2)   (x1, x2 bf16 -> out fp32)
// ---------------------------------------------------------------------------
__global__ __launch_bounds__(256)
void final_kernel(float* __restrict__ out, const ushort* __restrict__ x1,
                  const ushort* __restrict__ x2,
                  const float* __restrict__ alpha3, const float* __restrict__ beta3)
{
    const int blk = blockIdx.x;
    const int o = blk & 255;
    const float a = alpha3[o], bb = beta3[o];
    float2* po = reinterpret_cast<float2*>(out + (size_t)blk * NVV);
    const uint* p1 = reinterpret_cast<const uint*>(x1 + (size_t)blk * NVV);
    const uint* p2 = reinterpret_cast<const uint*>(x2 + (size_t)blk * NVV);
    for (int i = threadIdx.x; i < NVV / 2; i += 256) {
        float a1, b1, a2, b2;
        unpack2(p1[i], a1, b1);
        unpack2(p2[i], a2, b2);
        po[i] = make_float2(fmaxf(fmaf(a, a1, bb) + a2, 0.f),
                            fmaxf(fmaf(a, b1, bb) + b2, 0.f));
    }
}

// ---------------------------------------------------------------------------
extern "C" void kernel_launch(void* const* d_in, const int* in_sizes, int n_in,
                              void* d_out, int out_size, void* d_ws, size_t ws_size,
                              hipStream_t stream)
{
    (void)in_sizes; (void)n_in; (void)out_size;
    const float* x      = (const float*)d_in[0];
    const float* w1a    = (const float*)d_in[1];
    const float* g1a    = (const float*)d_in[3];
    const float* be1a   = (const float*)d_in[4];
    const float* coeffs = (const float*)d_in[5];
    const float* g2a    = (const float*)d_in[6];
    const float* be2a   = (const float*)d_in[7];
    const float* w3a    = (const float*)d_in[8];
    const float* g3a    = (const float*)d_in[10];
    const float* be3a   = (const float*)d_in[11];
    const float* w1b    = (const float*)d_in[12];
    const float* g1b    = (const float*)d_in[14];
    const float* be1b   = (const float*)d_in[15];
    const float* Gv     = (const float*)d_in[16];
    const float* Lv     = (const float*)d_in[17];
    const float* Fv     = (const float*)d_in[18];
    const float* EW     = (const float*)d_in[19];
    const float* NSm    = (const float*)d_in[20];
    const int*   Gc     = (const int*)d_in[22];
    const int*   Lc     = (const int*)d_in[24];
    const int*   Fc     = (const int*)d_in[26];

    char* base = (char*)d_ws;
    size_t off = 0;
    auto alloc = [&](size_t bytes) { char* p = base + off; off += (bytes + 255) & ~(size_t)255; return p; };

    // region0 timeline: gramPart+xsumPart -> gf (face/mesh) -> x1 (conv3/final)
    const size_t gfBytes = (size_t)BB * NFF * 2 * 128 * 2;       // 83.9 MB
    char* region0   = alloc(gfBytes);
    float* gramPart = (float*)region0;                            // 644*64KB = 42.2 MB
    float* xsumPart = (float*)(region0 + (size_t)GRAM_BLOCKS * 16384 * 4);
    ushort* gf      = (ushort*)region0;
    ushort* x1      = (ushort*)region0;                           // 42 MB, after gf dead

    ushort* xT      = (ushort*)alloc((size_t)BB * NVV * 128 * 2);
    ushort* h       = (ushort*)alloc((size_t)BB * NVV * 128 * 2);
    ushort* meshraw = (ushort*)alloc((size_t)BB * NVV * 128 * 2);
    ushort* x2      = (ushort*)alloc((size_t)BB * 256 * NVV * 2);
    uint*  cpk      = (uint*)alloc(32768 * 4);
    float* Gram     = (float*)alloc(16384 * 4);
    float* xsum     = (float*)alloc(128 * 4);
    float* alpha_a  = (float*)alloc(128 * 4);
    float* beta_a   = (float*)alloc(128 * 4);
    float* alpha_b  = (float*)alloc(256 * 4);
    float* beta_b   = (float*)alloc(256 * 4);
    float* alpha2   = (float*)alloc(128 * 4);
    float* beta2    = (float*)alloc(128 * 4);
    float* alpha3   = (float*)alloc(256 * 4);
    float* beta3    = (float*)alloc(256 * 4);
    float* msum     = (float*)alloc((size_t)648 * 128 * 4);
    float* mssq     = (float*)alloc((size_t)648 * 128 * 4);
    float* x1sum    = (float*)alloc((size_t)2 * 648 * 128 * 4);
    float* x1ssq    = (float*)alloc((size_t)2 * 648 * 128 * 4);
    if (off > ws_size) return;   // fail loud (validation will catch)

    gram_kernel<<<GRAM_BLOCKS, 256, 0, stream>>>(x, gramPart, xsumPart, (uint*)xT);
    reduce_gram_kernel<<<64, 256, 0, stream>>>(gramPart, xsumPart, Gram, xsum);
    stats_ab_kernel<<<384, 128, 0, stream>>>(Gram, xsum, w1a, g1a, be1a, w1b, g1b, be1b,
                                             alpha_a, beta_a, alpha_b, beta_b);
    prepack_coeffs_kernel<<<128, 256, 0, stream>>>(coeffs, cpk);
    mfma_conv_kernel<0><<<dim3(81, 8, 3), 256, 0, stream>>>(
        xT, w1a, w1b, nullptr, nullptr, alpha_a, beta_a, alpha_b, beta_b,
        h, x2, nullptr, nullptr, nullptr);
    face_kernel<<<dim3(NFF / 4, 8), 256, 0, stream>>>(h, Gv, Gc, EW, NSm, gf);
    mesh_gemm_kernel<<<dim3(81, 8), 512, 0, stream>>>(h, gf, (const uint4*)cpk,
                                                      Lv, Lc, Fv, Fc, meshraw, msum, mssq);
    finalize_stats_kernel<<<128, 256, 0, stream>>>(msum, mssq, 648, g2a, be2a, alpha2, beta2, 0);
    mfma_conv_kernel<1><<<dim3(81, 8, 2), 256, 0, stream>>>(
        meshraw, w3a, nullptr, alpha2, beta2, nullptr, nullptr, nullptr, nullptr,
        nullptr, nullptr, x1, x1sum, x1ssq);
    finalize_stats_kernel<<<256, 256, 0, stream>>>(x1sum, x1ssq, 648, g3a, be3a, alpha3, beta3, 1);
    final_kernel<<<2048, 256, 0, stream>>>((float*)d_out, x1, x2, alpha3, beta3);
}